// Round 3
// baseline (3113.539 us; speedup 1.0000x reference)
//
#include <hip/hip_runtime.h>
#include <cmath>

// Shapes (fixed by the problem)
#define Bb   4
#define Tt   288      // NV(256) + NQ(32)
#define Dd   1024
#define DIi  2048
#define HH   32
#define PP   64
#define NNs  128
#define PROJ  4384    // 2*DI + 2*N + H (logical)
#define PROJP 4480    // padded to 35*128 for MFMA tiles
#define NLl  12
#define EE   1536

typedef __bf16 bf16x8 __attribute__((ext_vector_type(8)));
typedef float f32x4 __attribute__((ext_vector_type(4)));
typedef float f32x16 __attribute__((ext_vector_type(16)));

__device__ __forceinline__ unsigned short f2bf(float v) {
  __bf16 b = (__bf16)v;
  return __builtin_bit_cast(unsigned short, b);
}
__device__ __forceinline__ float bf2f(unsigned short u) {
  unsigned int x = ((unsigned int)u) << 16;
  return __builtin_bit_cast(float, x);
}
// split fp32 -> (hi, lo) bf16 pair: v ~= hi + lo to ~16 mantissa bits
__device__ __forceinline__ void split2(float v, unsigned short& h, unsigned short& l) {
  h = f2bf(v);
  l = f2bf(v - bf2f(h));
}

// ---- fragment-major packed bf16 layout --------------------------------------
// Matrix [R][K] stored as 32x32 tiles (2048 B each), row-block-major:
//   tile = (row>>5)*(K>>5) + (k>>5)
// within tile, matching mfma_f32_32x32x16_bf16 operand order:
//   half = (k>>4)&1, lane = (row&31) + (((k>>3)&1)<<5), j = k&7
//   elem offset = tile*1024 + half*512 + lane*8 + j
// => fragment read (LDS or GLOBAL) is base + lane*16B: conflict-free/coalesced.
__device__ __forceinline__ size_t packed_off(int row, int k, int K) {
  size_t tile = (size_t)(row >> 5) * (K >> 5) + (k >> 5);
  int half = (k >> 4) & 1;
  int lane = (row & 31) + (((k >> 3) & 1) << 5);
  return tile * 1024 + half * 512 + lane * 8 + (k & 7);
}

// async global->LDS, 16B per lane (lane-linear LDS layout required)
__device__ __forceinline__ void async16(const void* g, void* l) {
  __builtin_amdgcn_global_load_lds(
      (const __attribute__((address_space(1))) unsigned int*)g,
      (__attribute__((address_space(3))) unsigned int*)l, 16, 0, 0);
}

// ---------------- block reduction helper ----------------
__device__ inline float block_reduce_sum(float v, float* lds) {
#pragma unroll
  for (int d = 32; d > 0; d >>= 1) v += __shfl_down(v, d, 64);
  int lane = threadIdx.x & 63;
  int w = threadIdx.x >> 6;
  if (lane == 0) lds[w] = v;
  __syncthreads();
  if (threadIdx.x == 0) {
    float s = lds[0];
    int nw = blockDim.x >> 6;
    for (int i = 1; i < nw; i++) s += lds[i];
    lds[0] = s;
  }
  __syncthreads();
  return lds[0];
}

// ---------------- fp32 -> bf16 hi/lo (activations, vis+qry fused, packed) ----------------
__global__ __launch_bounds__(256) void cvt_act_k(const float* __restrict__ vis,
                                                 const float* __restrict__ qry,
                                                 unsigned short* __restrict__ oh,
                                                 unsigned short* __restrict__ ol) {
  int idx = (blockIdx.x * 256 + threadIdx.x) * 8;
  const float* src = (idx < 1024 * 1024) ? &vis[idx] : &qry[idx - 1024 * 1024];
  float4 v0 = *(const float4*)&src[0];
  float4 v1 = *(const float4*)&src[4];
  ushort4 h0, l0, h1, l1;
  split2(v0.x, h0.x, l0.x); split2(v0.y, h0.y, l0.y);
  split2(v0.z, h0.z, l0.z); split2(v0.w, h0.w, l0.w);
  split2(v1.x, h1.x, l1.x); split2(v1.y, h1.y, l1.y);
  split2(v1.z, h1.z, l1.z); split2(v1.w, h1.w, l1.w);
  size_t po = packed_off(idx >> 10, idx & 1023, 1024);   // k%8==0 -> 8 contiguous
  *(ushort4*)&oh[po] = h0; *(ushort4*)&oh[po + 4] = h1;
  *(ushort4*)&ol[po] = l0; *(ushort4*)&ol[po + 4] = l1;
}

// ---------------- W fp32 [K][N] -> packed hi/lo bf16 [Npad rows][K] ----------------
// Block handles 32 n x 64 k; writers emit 16B contiguous per buffer (full wave
// covers a 2KB packed tile linearly -> coalesced stores).
__global__ __launch_bounds__(256) void cvt_tr2_k(const float* __restrict__ W,
                                                 unsigned short* __restrict__ Wth,
                                                 unsigned short* __restrict__ Wtl,
                                                 int K, int N,
                                                 size_t wstride, size_t ostride) {
  __shared__ float tile[64][33];
  W   += (size_t)blockIdx.z * wstride;
  Wth += (size_t)blockIdx.z * ostride;
  Wtl += (size_t)blockIdx.z * ostride;
  const int n0 = blockIdx.x * 32, k0 = blockIdx.y * 64;
  const int c = threadIdx.x & 31;
  const int r0 = threadIdx.x >> 5;   // 0..7
#pragma unroll
  for (int j = 0; j < 8; j++) {
    int r = r0 + j * 8;              // 0..63
    int n = n0 + c;
    tile[r][c] = (n < N) ? W[(size_t)(k0 + r) * N + n] : 0.f;
  }
  __syncthreads();
  const int nl = threadIdx.x & 31;
  const int kg = threadIdx.x >> 5;   // 0..7 -> k = kg*8 .. +7
  unsigned short h[8], l[8];
#pragma unroll
  for (int j = 0; j < 8; j++) split2(tile[kg * 8 + j][nl], h[j], l[j]);
  size_t o = packed_off(n0 + nl, k0 + kg * 8, K);   // 8 contiguous elems (16B)
  *(ushort4*)&Wth[o]     = make_ushort4(h[0], h[1], h[2], h[3]);
  *(ushort4*)&Wth[o + 4] = make_ushort4(h[4], h[5], h[6], h[7]);
  *(ushort4*)&Wtl[o]     = make_ushort4(l[0], l[1], l[2], l[3]);
  *(ushort4*)&Wtl[o + 4] = make_ushort4(l[4], l[5], l[6], l[7]);
}

// ---------------- split-bf16 MFMA GEMM, packed operands, 3-term ----------------
// A-frags load DIRECTLY global->reg (packed layout == fragment layout, A is
// L2-resident): halves LDS read traffic. B double-buffered in LDS via
// global_load_lds; one barrier per k-step pair phase (2-phase pipeline).
template<int BM, int BN>
__global__ __launch_bounds__(256) void gemm3_k(
    const unsigned short* __restrict__ Ah, const unsigned short* __restrict__ Al,
    const unsigned short* __restrict__ Wh, const unsigned short* __restrict__ Wl,
    const float* __restrict__ bias, const float* __restrict__ res,
    float* __restrict__ C, int M, int N, int K,
    int rows_per_b, int T_total, int t_off)
{
  constexpr int FM = BM / 64;   // 32-row frags per wave (m)
  constexpr int FN = BN / 64;   // 32-col frags per wave (n)
  __shared__ __align__(16) unsigned short Bsh0[BN * 32];
  __shared__ __align__(16) unsigned short Bsl0[BN * 32];
  __shared__ __align__(16) unsigned short Bsh1[BN * 32];
  __shared__ __align__(16) unsigned short Bsl1[BN * 32];
  const int tid = threadIdx.x;
  const int lane = tid & 63;
  const int wm = (tid >> 6) >> 1;
  const int wn = (tid >> 6) & 1;
  const int m0 = blockIdx.y * BM;
  const int n0 = blockIdx.x * BN;
  const int lrow = lane & 31;
  const int kb32 = K >> 5;

  f32x16 acc[FM][FN];
#pragma unroll
  for (int i = 0; i < FM; i++)
#pragma unroll
    for (int j = 0; j < FN; j++) acc[i][j] = (f32x16)0.0f;

  auto stageB = [&](unsigned short* dH, unsigned short* dL, int kb) {
#pragma unroll
    for (int c = 0; c < BN / 64; c++) {
      int o = (c * 256 + tid) * 16;   // byte offset
      int t = o >> 11;                // which 32-row tile
      size_t gb = (((size_t)((n0 >> 5) + t) * kb32 + kb) << 11) + (o & 2047);
      async16((const char*)Wh + gb, (char*)dH + o);
      async16((const char*)Wl + gb, (char*)dL + o);
    }
  };
  bf16x8 a0h[FM][2], a0l[FM][2], a1h[FM][2], a1l[FM][2];
  auto loadA = [&](bf16x8 (&rh)[FM][2], bf16x8 (&rl)[FM][2], int kb) {
#pragma unroll
    for (int i = 0; i < FM; i++)
#pragma unroll
      for (int kh = 0; kh < 2; kh++) {
        size_t ga = ((size_t)((m0 >> 5) + wm * FM + i) * kb32 + kb) * 1024
                  + kh * 512 + (size_t)lane * 8;
        rh[i][kh] = *(const bf16x8*)&Ah[ga];
        rl[i][kh] = *(const bf16x8*)&Al[ga];
      }
  };
  auto compute = [&](bf16x8 (&rh)[FM][2], bf16x8 (&rl)[FM][2],
                     const unsigned short* BH, const unsigned short* BL) {
#pragma unroll
    for (int kh = 0; kh < 2; kh++) {
      bf16x8 bh[FN], bl[FN];
#pragma unroll
      for (int j = 0; j < FN; j++) {
        int off = (wn * FN + j) * 1024 + kh * 512 + lane * 8;
        bh[j] = *(const bf16x8*)&BH[off];
        bl[j] = *(const bf16x8*)&BL[off];
      }
#pragma unroll
      for (int i = 0; i < FM; i++)
#pragma unroll
        for (int j = 0; j < FN; j++) {
          acc[i][j] = __builtin_amdgcn_mfma_f32_32x32x16_bf16(rh[i][kh], bh[j], acc[i][j], 0, 0, 0);
          acc[i][j] = __builtin_amdgcn_mfma_f32_32x32x16_bf16(rh[i][kh], bl[j], acc[i][j], 0, 0, 0);
          acc[i][j] = __builtin_amdgcn_mfma_f32_32x32x16_bf16(rl[i][kh], bh[j], acc[i][j], 0, 0, 0);
        }
    }
  };

  stageB(Bsh0, Bsl0, 0);
  loadA(a0h, a0l, 0);
  __syncthreads();
  for (int kb = 0; kb < kb32; kb += 2) {   // kb32 is even (32 or 64)
    stageB(Bsh1, Bsl1, kb + 1);
    loadA(a1h, a1l, kb + 1);
    compute(a0h, a0l, Bsh0, Bsl0);
    __syncthreads();
    if (kb + 2 < kb32) { stageB(Bsh0, Bsl0, kb + 2); loadA(a0h, a0l, kb + 2); }
    compute(a1h, a1l, Bsh1, Bsl1);
    __syncthreads();
  }

  // epilogue: 32x32 C/D layout = col=lane&31, row=(rg&3)+8*(rg>>2)+4*(lane>>5)
  const int r0 = (lane >> 5) * 4;
#pragma unroll
  for (int i = 0; i < FM; i++) {
#pragma unroll
    for (int j = 0; j < FN; j++) {
      int ncol = n0 + wn * (BN / 2) + j * 32 + lrow;
      float bv = bias ? bias[ncol] : 0.f;
#pragma unroll
      for (int rg = 0; rg < 16; rg++) {
        int m = m0 + wm * (BM / 2) + i * 32 + (rg & 3) + 8 * (rg >> 2) + r0;
        size_t orow;
        if (T_total) {
          int bbv = m / rows_per_b;
          orow = (size_t)bbv * T_total + (m - bbv * rows_per_b) + t_off;
        } else {
          orow = (size_t)m;
        }
        float v = acc[i][j][rg] + bv;
        if (res) v += res[orow * N + ncol];
        C[orow * N + ncol] = v;
      }
    }
  }
}

// ---------------- general tiled fp32 GEMM (tiny head matmul only) ----------------
__global__ __launch_bounds__(256) void gemm_k(
    const float* __restrict__ A, const float* __restrict__ W,
    const float* __restrict__ bias, const float* __restrict__ res,
    float* __restrict__ C, int M, int N, int K,
    int rows_per_b, int T_total, int t_off)
{
  __shared__ float As[16][64];
  __shared__ float Ws[16][64];
  const int tid = threadIdx.x;
  const int tx = tid & 15;
  const int ty = tid >> 4;
  const int m0 = blockIdx.y * 64;
  const int n0 = blockIdx.x * 64;
  float acc[4][4] = {};
  const int ar = tid >> 2;
  const int ac = (tid & 3) << 2;
  const int wr = tid >> 4;
  const int wc = (tid & 15) << 2;

  for (int k0 = 0; k0 < K; k0 += 16) {
    float4 av = {0.f, 0.f, 0.f, 0.f};
    int gr = m0 + ar;
    if (gr < M) av = *(const float4*)&A[(size_t)gr * K + k0 + ac];
    As[ac + 0][ar] = av.x; As[ac + 1][ar] = av.y;
    As[ac + 2][ar] = av.z; As[ac + 3][ar] = av.w;

    float4 wv = {0.f, 0.f, 0.f, 0.f};
    int gc = n0 + wc;
    const float* wp = &W[(size_t)(k0 + wr) * N + gc];
    if (gc + 3 < N) {
      wv = *(const float4*)wp;
    } else {
      if (gc + 0 < N) wv.x = wp[0];
      if (gc + 1 < N) wv.y = wp[1];
      if (gc + 2 < N) wv.z = wp[2];
    }
    *(float4*)&Ws[wr][wc] = wv;
    __syncthreads();
#pragma unroll
    for (int kk = 0; kk < 16; kk++) {
      float4 a4 = *(const float4*)&As[kk][ty << 2];
      float4 b4 = *(const float4*)&Ws[kk][tx << 2];
      float a[4] = {a4.x, a4.y, a4.z, a4.w};
      float b[4] = {b4.x, b4.y, b4.z, b4.w};
#pragma unroll
      for (int i = 0; i < 4; i++)
#pragma unroll
        for (int j = 0; j < 4; j++)
          acc[i][j] = fmaf(a[i], b[j], acc[i][j]);
    }
    __syncthreads();
  }
#pragma unroll
  for (int i = 0; i < 4; i++) {
    int gr = m0 + (ty << 2) + i;
    if (gr >= M) continue;
    int bbv = gr / rows_per_b;
    int tt = gr - bbv * rows_per_b;
    size_t orow = (size_t)bbv * T_total + tt + t_off;
#pragma unroll
    for (int j = 0; j < 4; j++) {
      int gc = n0 + (tx << 2) + j;
      if (gc >= N) continue;
      float v = acc[i][j];
      if (bias) v += bias[gc];
      if (res)  v += res[orow * (size_t)N + gc];
      C[orow * (size_t)N + gc] = v;
    }
  }
}

// ---------------- RMSNorm (fp32 out, for final norm) ----------------
__global__ __launch_bounds__(256) void rmsnorm_k(
    const float* __restrict__ x, const float* __restrict__ w, float* __restrict__ out)
{
  __shared__ float lds[8];
  const int row = blockIdx.x;
  const float* xr = x + (size_t)row * Dd;
  float4 v = *(const float4*)&xr[threadIdx.x << 2];
  float ss = v.x * v.x + v.y * v.y + v.z * v.z + v.w * v.w;
  ss = block_reduce_sum(ss, lds);
  float sc = rsqrtf(ss * (1.f / Dd) + 1e-5f);
  float4 wv = *(const float4*)&w[threadIdx.x << 2];
  float4 o = {v.x * sc * wv.x, v.y * sc * wv.y, v.z * sc * wv.z, v.w * sc * wv.w};
  *(float4*)&out[(size_t)row * Dd + (threadIdx.x << 2)] = o;
}

// ---------------- RMSNorm (packed bf16 hi/lo out, feeds split GEMM) ----------------
__global__ __launch_bounds__(256) void rmsnorm2_k(
    const float* __restrict__ x, const float* __restrict__ w,
    unsigned short* __restrict__ oh, unsigned short* __restrict__ ol)
{
  __shared__ float lds[8];
  const int row = blockIdx.x;
  const float* xr = x + (size_t)row * Dd;
  float4 v = *(const float4*)&xr[threadIdx.x << 2];
  float ss = v.x * v.x + v.y * v.y + v.z * v.z + v.w * v.w;
  ss = block_reduce_sum(ss, lds);
  float sc = rsqrtf(ss * (1.f / Dd) + 1e-5f);
  float4 wv = *(const float4*)&w[threadIdx.x << 2];
  ushort4 h, l;
  split2(v.x * sc * wv.x, h.x, l.x);
  split2(v.y * sc * wv.y, h.y, l.y);
  split2(v.z * sc * wv.z, h.z, l.z);
  split2(v.w * sc * wv.w, h.w, l.w);
  size_t o = packed_off(row, threadIdx.x << 2, 1024);
  *(ushort4*)&oh[o] = h;
  *(ushort4*)&ol[o] = l;
}

// ---------------- merged: dtcum (y==9) + cbgemm (y<9) ----------------
// Both only READ proj; writes are disjoint -> safe to fuse into one dispatch.
__global__ __launch_bounds__(256) void sscb_k(const float* __restrict__ proj,
                                              const float* __restrict__ dt_bias,
                                              const float* __restrict__ A_log,
                                              float* __restrict__ dtt,
                                              double* __restrict__ dcum,
                                              float* __restrict__ St)
{
  __shared__ float Ct[32][130];
  __shared__ float Bt[32][130];
  if (blockIdx.y == 9) {
    // dt = softplus(.), cum = prefix-sum(dt*A) in fp64; wave per (b,h)
    if (blockIdx.x >= 8) return;
    const int wv = threadIdx.x >> 6;
    const int lane = threadIdx.x & 63;
    const int h = blockIdx.x * 4 + wv;
    const int b = blockIdx.z;
    const float A = -expf(A_log[h]);
    const float bias = dt_bias[h];
    const int rowo = (b * HH + h) * Tt;
    double base = 0.0;
    for (int c = 0; c < (Tt + 63) / 64; c++) {
      int t = c * 64 + lane;
      float dt = 0.f;
      if (t < Tt) {
        float v = proj[(size_t)(b * Tt + t) * PROJP + 2 * DIi + 2 * NNs + h] + bias;
        dt = (v > 20.f) ? v : log1pf(expf(v));
      }
      double a = (double)(dt * A);
#pragma unroll
      for (int d = 1; d < 64; d <<= 1) {
        double o = __shfl_up(a, d, 64);
        if (lane >= d) a += o;
      }
      double cum = base + a;
      if (t < Tt) { dtt[rowo + t] = dt; dcum[rowo + t] = cum; }
      base = __shfl(cum, 63, 64);
    }
    return;
  }
  // St[b][j][t] = B[b,j,:]·C[b,t,:] (32x32 tiles, causal only)
  const int tI = blockIdx.x, jI = blockIdx.y, b = blockIdx.z;
  if (jI > tI) return;
  const int tid = threadIdx.x;
  const int r = tid >> 3;          // 0..31
  const int q = (tid & 7) * 16;    // 16 floats each
  const float* pb = proj + (size_t)b * Tt * PROJP;
  {
    const float* crow = pb + (size_t)(tI * 32 + r) * PROJP + 2 * DIi + NNs + q;
    const float* brow = pb + (size_t)(jI * 32 + r) * PROJP + 2 * DIi + q;
#pragma unroll
    for (int f = 0; f < 16; f += 4) {
      float4 c4 = *(const float4*)&crow[f];
      float4 b4 = *(const float4*)&brow[f];
      *(float2*)&Ct[r][q + f]     = make_float2(c4.x, c4.y);
      *(float2*)&Ct[r][q + f + 2] = make_float2(c4.z, c4.w);
      *(float2*)&Bt[r][q + f]     = make_float2(b4.x, b4.y);
      *(float2*)&Bt[r][q + f + 2] = make_float2(b4.z, b4.w);
    }
  }
  __syncthreads();
  const int j_r = tid >> 3;
  const int t_c = (tid & 7) * 4;
  float acc[4] = {0.f, 0.f, 0.f, 0.f};
  for (int n = 0; n < NNs; n += 2) {
    float2 b2 = *(const float2*)&Bt[j_r][n];
#pragma unroll
    for (int k = 0; k < 4; k++) {
      float2 c2 = *(const float2*)&Ct[t_c + k][n];
      acc[k] = fmaf(b2.x, c2.x, acc[k]);
      acc[k] = fmaf(b2.y, c2.y, acc[k]);
    }
  }
  float* so = St + ((size_t)b * Tt + jI * 32 + j_r) * Tt + tI * 32 + t_c;
  *(float4*)so = make_float4(acc[0], acc[1], acc[2], acc[3]);
}

// ---------------- Y[b,t,h,:] = sum_j M(t,j) * X[b,j,h,:]  (causal, decay-scaled) ----------------
__global__ __launch_bounds__(256) void ssd_y_k(
    const float* __restrict__ proj, const float* __restrict__ St,
    const float* __restrict__ dtt, const double* __restrict__ dcum,
    const float* __restrict__ Dssm, float* __restrict__ ybuf)
{
  const int tI = blockIdx.x;          // 0..8
  const int h  = blockIdx.y;
  const int b  = blockIdx.z;
  __shared__ __align__(16) float Xs[32][64];
  __shared__ __align__(16) float Ss[32][36];
  __shared__ double cjs[32];
  const int tid = threadIdx.x;
  const int t_l = tid & 31;
  const int pg  = tid >> 5;           // 0..7
  const int t0  = tI * 32;
  const int rowo = (b * HH + h) * Tt;
  const double ct = dcum[rowo + t0 + t_l];
  const float Ds = Dssm[h];
  const float* pb = proj + (size_t)b * Tt * PROJP;
  float y[8] = {0,0,0,0,0,0,0,0};
  const int sr = tid >> 3;
  const int sq = tid & 7;

  for (int jI = 0; jI <= tI; jI++) {
    const int j0 = jI * 32;
    {
      const float* xr = pb + (size_t)(j0 + sr) * PROJP + DIi + h * PP + sq * 8;
      *(float4*)&Xs[sr][sq * 8]     = *(const float4*)&xr[0];
      *(float4*)&Xs[sr][sq * 8 + 4] = *(const float4*)&xr[4];
    }
    {
      const float* srow = St + ((size_t)b * Tt + j0 + sr) * Tt + t0 + sq * 4;
      float4 s4 = *(const float4*)srow;
      float dj = dtt[rowo + j0 + sr];
      s4.x *= dj; s4.y *= dj; s4.z *= dj; s4.w *= dj;
      *(float4*)&Ss[sr][sq * 4] = s4;
    }
    if (tid < 32) cjs[tid] = dcum[rowo + j0 + tid];
    __syncthreads();

    if (jI < tI) {
#pragma unroll 4
      for (int j = 0; j < 32; j++) {
        float d = (float)(ct - cjs[j]);
        float m = Ss[j][t_l] * expf(fminf(d, 0.f));
        const float* xp = &Xs[j][pg * 8];
        float4 a0 = *(const float4*)&xp[0];
        float4 a1 = *(const float4*)&xp[4];
        y[0] = fmaf(m, a0.x, y[0]); y[1] = fmaf(m, a0.y, y[1]);
        y[2] = fmaf(m, a0.z, y[2]); y[3] = fmaf(m, a0.w, y[3]);
        y[4] = fmaf(m, a1.x, y[4]); y[5] = fmaf(m, a1.y, y[5]);
        y[6] = fmaf(m, a1.z, y[6]); y[7] = fmaf(m, a1.w, y[7]);
      }
    } else {
      for (int j = 0; j < 32; j++) {
        float sv = Ss[j][t_l];
        float d = (float)(ct - cjs[j]);
        float m = sv * expf(fminf(d, 0.f));
        if (j == t_l) m = 0.5f * sv + Ds;
        if (j > t_l)  m = 0.f;
        const float* xp = &Xs[j][pg * 8];
        float4 a0 = *(const float4*)&xp[0];
        float4 a1 = *(const float4*)&xp[4];
        y[0] = fmaf(m, a0.x, y[0]); y[1] = fmaf(m, a0.y, y[1]);
        y[2] = fmaf(m, a0.z, y[2]); y[3] = fmaf(m, a0.w, y[3]);
        y[4] = fmaf(m, a1.x, y[4]); y[5] = fmaf(m, a1.y, y[5]);
        y[6] = fmaf(m, a1.z, y[6]); y[7] = fmaf(m, a1.w, y[7]);
      }
    }
    __syncthreads();
  }
  float* yo = &ybuf[(size_t)(b * Tt + t0 + t_l) * DIi + h * PP + pg * 8];
  *(float4*)&yo[0] = make_float4(y[0], y[1], y[2], y[3]);
  *(float4*)&yo[4] = make_float4(y[4], y[5], y[6], y[7]);
}

// ---------------- fused silu-gate + RMSNorm over DI=2048, packed bf16 out ----------------
__global__ __launch_bounds__(256) void gate_norm2_k(
    const float* __restrict__ ybuf, const float* __restrict__ proj,
    const float* __restrict__ gw,
    unsigned short* __restrict__ yh, unsigned short* __restrict__ yl)
{
  __shared__ float lds[8];
  const int row = blockIdx.x;
  const float* yr = ybuf + (size_t)row * DIi;
  const float* zr = proj + (size_t)row * PROJP;   // z = cols [0, 2048)
  const int base = threadIdx.x << 3;
  float4 z0 = *(const float4*)&zr[base];
  float4 z1 = *(const float4*)&zr[base + 4];
  float4 y0 = *(const float4*)&yr[base];
  float4 y1 = *(const float4*)&yr[base + 4];
  float zz[8] = {z0.x, z0.y, z0.z, z0.w, z1.x, z1.y, z1.z, z1.w};
  float yy[8] = {y0.x, y0.y, y0.z, y0.w, y1.x, y1.y, y1.z, y1.w};
  float g[8];
  float ss = 0.f;
#pragma unroll
  for (int e = 0; e < 8; e++) {
    float s = zz[e] / (1.f + expf(-zz[e]));
    float gv = yy[e] * s;
    g[e] = gv;
    ss += gv * gv;
  }
  ss = block_reduce_sum(ss, lds);
  float sc = rsqrtf(ss * (1.f / DIi) + 1e-5f);
  ushort4 h0, l0, h1, l1;
  split2(g[0] * sc * gw[base + 0], h0.x, l0.x);
  split2(g[1] * sc * gw[base + 1], h0.y, l0.y);
  split2(g[2] * sc * gw[base + 2], h0.z, l0.z);
  split2(g[3] * sc * gw[base + 3], h0.w, l0.w);
  split2(g[4] * sc * gw[base + 4], h1.x, l1.x);
  split2(g[5] * sc * gw[base + 5], h1.y, l1.y);
  split2(g[6] * sc * gw[base + 6], h1.z, l1.z);
  split2(g[7] * sc * gw[base + 7], h1.w, l1.w);
  size_t o = packed_off(row, base, 2048);   // base%8==0 -> 8 contiguous elems
  *(ushort4*)&yh[o] = h0; *(ushort4*)&yh[o + 4] = h1;
  *(ushort4*)&yl[o] = l0; *(ushort4*)&yl[o + 4] = l1;
}

// ---------------- mean over T ----------------
__global__ void pool_k(const float* __restrict__ xin, float* __restrict__ pooled) {
  int b = blockIdx.x;
  int d = blockIdx.y * 256 + threadIdx.x;
  const float* base = xin + (size_t)b * Tt * Dd + d;
  float s = 0.f;
  for (int t = 0; t < Tt; t++) s += base[(size_t)t * Dd];
  pooled[b * Dd + d] = s * (1.f / Tt);
}

// ---------------- L2-normalize rows of (4, 1536), in place ----------------
__global__ __launch_bounds__(256) void l2norm_k(float* __restrict__ out) {
  __shared__ float lds[8];
  const int row = blockIdx.x;
  float* r = out + (size_t)row * EE;
  float v[6];
  float ss = 0.f;
#pragma unroll
  for (int e = 0; e < 6; e++) {
    v[e] = r[(e << 8) + threadIdx.x];
    ss += v[e] * v[e];
  }
  ss = block_reduce_sum(ss, lds);
  float sc = 1.f / fmaxf(sqrtf(ss), 1e-12f);
#pragma unroll
  for (int e = 0; e < 6; e++) r[(e << 8) + threadIdx.x] = v[e] * sc;
}

// ---------------- launch ----------------
extern "C" void kernel_launch(void* const* d_in, const int* in_sizes, int n_in,
                              void* d_out, int out_size, void* d_ws, size_t ws_size,
                              hipStream_t stream) {
  (void)in_sizes; (void)n_in; (void)out_size;
  const float* visual   = (const float*)d_in[0];
  const float* query    = (const float*)d_in[1];
  const float* vis_w    = (const float*)d_in[2];
  const float* vis_b    = (const float*)d_in[3];
  const float* qry_w    = (const float*)d_in[4];
  const float* qry_b    = (const float*)d_in[5];
  const float* norm_ws  = (const float*)d_in[6];
  const float* in_ws    = (const float*)d_in[7];
  const float* dt_biases= (const float*)d_in[8];
  const float* A_logs   = (const float*)d_in[9];
  const float* D_ssm    = (const float*)d_in[10];
  const float* gnorm_ws = (const float*)d_in[11];
  const float* out_ws   = (const float*)d_in[12];
  const float* norm_f_w = (const float*)d_in[13];
  const float* head_w   = (const float*)d_in[14];
  const float* head_b   = (const float*)d_in[15];
  float* out = (float*)d_out;

  // workspace layout (bytes), all 16B-aligned; base ~69 MB
  char* w = (char*)d_ws;
  float*          hidden = (float*)w;          w += (size_t)1152 * 1024 * 4;
  unsigned short* xh     = (unsigned short*)w; w += (size_t)1152 * 1024 * 2;
  unsigned short* xl     = (unsigned short*)w; w += (size_t)1152 * 1024 * 2;
  float*          proj   = (float*)w;          w += (size_t)1152 * PROJP * 4;
  float*          ybuf   = (float*)w;          w += (size_t)1152 * 2048 * 4;
  unsigned short* yh     = (unsigned short*)w; w += (size_t)1152 * 2048 * 2;
  unsigned short* yl     = (unsigned short*)w; w += (size_t)1152 * 2048 * 2;
  float*          dtt    = (float*)w;          w += (size_t)Bb * HH * Tt * 4;
  double*         dcum   = (double*)w;         w += (size_t)Bb * HH * Tt * 8;
  float*          Stb    = (float*)w;          w += (size_t)Bb * Tt * Tt * 4;
  float*          pooled = (float*)w;          w += (size_t)4096 * 4;
  unsigned short* wth    = (unsigned short*)w; w += (size_t)PROJP * 1024 * 2;
  unsigned short* wtl    = (unsigned short*)w; w += (size_t)PROJP * 1024 * 2;

  // extended region: all-layer pre-converted weights (~330 MB)
  unsigned short* wtin_h  = (unsigned short*)w; w += (size_t)NLl * PROJP * 1024 * 2;
  unsigned short* wtin_l  = (unsigned short*)w; w += (size_t)NLl * PROJP * 1024 * 2;
  unsigned short* wtout_h = (unsigned short*)w; w += (size_t)NLl * 1024 * 2048 * 2;
  unsigned short* wtout_l = (unsigned short*)w; w += (size_t)NLl * 1024 * 2048 * 2;
  unsigned short* wtv_h   = (unsigned short*)w; w += (size_t)1024 * 1024 * 2;
  unsigned short* wtv_l   = (unsigned short*)w; w += (size_t)1024 * 1024 * 2;
  unsigned short* wtq_h   = (unsigned short*)w; w += (size_t)1024 * 1024 * 2;
  unsigned short* wtq_l   = (unsigned short*)w; w += (size_t)1024 * 1024 * 2;
  const bool batched = ((size_t)(w - (char*)d_ws)) <= ws_size;

  dim3 blk(256);

  // ---- activations -> packed split bf16 (vis+qry in one launch) ----
  cvt_act_k<<<576, blk, 0, stream>>>(visual, query, xh, xl);

  if (batched) {
    // ---- all weight conversions upfront (4 launches instead of 24 in-loop) ----
    cvt_tr2_k<<<dim3(32, 16, 1), blk, 0, stream>>>(vis_w, wtv_h, wtv_l, 1024, 1024, 0, 0);
    cvt_tr2_k<<<dim3(32, 16, 1), blk, 0, stream>>>(qry_w, wtq_h, wtq_l, 1024, 1024, 0, 0);
    cvt_tr2_k<<<dim3(PROJP / 32, 16, NLl), blk, 0, stream>>>(
        in_ws, wtin_h, wtin_l, Dd, PROJ, (size_t)Dd * PROJ, (size_t)PROJP * 1024);
    cvt_tr2_k<<<dim3(32, 32, NLl), blk, 0, stream>>>(
        out_ws, wtout_h, wtout_l, DIi, Dd, (size_t)DIi * Dd, (size_t)1024 * 2048);
    gemm3_k<128, 64><<<dim3(16, 8), blk, 0, stream>>>(
        xh, xl, wtv_h, wtv_l, vis_b, nullptr, hidden, 1024, 1024, 1024, 256, Tt, 0);
    gemm3_k<128, 64><<<dim3(16, 1), blk, 0, stream>>>(
        xh + (size_t)1024 * 1024, xl + (size_t)1024 * 1024, wtq_h, wtq_l,
        qry_b, nullptr, hidden, 128, 1024, 1024, 32, Tt, 256);
  } else {
    cvt_tr2_k<<<dim3(32, 16, 1), blk, 0, stream>>>(vis_w, wth, wtl, 1024, 1024, 0, 0);
    gemm3_k<128, 64><<<dim3(16, 8), blk, 0, stream>>>(
        xh, xl, wth, wtl, vis_b, nullptr, hidden, 1024, 1024, 1024, 256, Tt, 0);
    cvt_tr2_k<<<dim3(32, 16, 1), blk, 0, stream>>>(qry_w, wth, wtl, 1024, 1024, 0, 0);
    gemm3_k<128, 64><<<dim3(16, 1), blk, 0, stream>>>(
        xh + (size_t)1024 * 1024, xl + (size_t)1024 * 1024, wth, wtl,
        qry_b, nullptr, hidden, 128, 1024, 1024, 32, Tt, 256);
  }

  for (int i = 0; i < NLl; i++) {
    rmsnorm2_k<<<Bb * Tt, blk, 0, stream>>>(hidden, norm_ws + i * Dd, xh, xl);
    // in-proj: packed W [4480][1024]; C = proj [1152][4480]
    const unsigned short *bih, *bil;
    if (batched) {
      bih = wtin_h + (size_t)i * PROJP * 1024;
      bil = wtin_l + (size_t)i * PROJP * 1024;
    } else {
      cvt_tr2_k<<<dim3(PROJP / 32, 16, 1), blk, 0, stream>>>(
          in_ws + (size_t)i * Dd * PROJ, wth, wtl, Dd, PROJ, 0, 0);
      bih = wth; bil = wtl;
    }
    gemm3_k<128, 128><<<dim3(PROJP / 128, 9), blk, 0, stream>>>(
        xh, xl, bih, bil, nullptr, nullptr, proj, 1152, PROJP, Dd, 1152, 0, 0);
    // SSD quadratic form: merged dtcum + cbgemm, then ssd_y
    sscb_k<<<dim3(9, 10, Bb), blk, 0, stream>>>(proj, dt_biases + i * HH,
                                                A_logs + i * HH, dtt, dcum, Stb);
    ssd_y_k<<<dim3(9, HH, Bb), blk, 0, stream>>>(proj, Stb, dtt, dcum,
                                                 D_ssm + i * HH, ybuf);
    gate_norm2_k<<<Bb * Tt, blk, 0, stream>>>(ybuf, proj, gnorm_ws + i * DIi, yh, yl);
    // out-proj: packed W [1024][2048]; C = hidden (+res)
    const unsigned short *boh, *bol;
    if (batched) {
      boh = wtout_h + (size_t)i * 1024 * 2048;
      bol = wtout_l + (size_t)i * 1024 * 2048;
    } else {
      cvt_tr2_k<<<dim3(32, 32, 1), blk, 0, stream>>>(
          out_ws + (size_t)i * DIi * Dd, wth, wtl, DIi, Dd, 0, 0);
      boh = wth; bol = wtl;
    }
    gemm3_k<128, 64><<<dim3(16, 9), blk, 0, stream>>>(
        yh, yl, boh, bol, nullptr, hidden, hidden, 1152, Dd, DIi, 1152, 0, 0);
  }

  rmsnorm_k<<<Bb * Tt, blk, 0, stream>>>(hidden, norm_f_w, ybuf);
  pool_k<<<dim3(Bb, 4), blk, 0, stream>>>(ybuf, pooled);
  gemm_k<<<dim3(24, 1), blk, 0, stream>>>(pooled, head_w, head_b, nullptr, out,
                                          Bb, EE, Dd, Bb, 0, 0);
  l2norm_k<<<Bb, blk, 0, stream>>>(out);
}

// Round 4
// 2738.061 us; speedup vs baseline: 1.1371x; 1.1371x over previous
//
#include <hip/hip_runtime.h>
#include <cmath>

// Shapes (fixed by the problem)
#define Bb   4
#define Tt   288      // NV(256) + NQ(32)
#define Dd   1024
#define DIi  2048
#define HH   32
#define PP   64
#define NNs  128
#define PROJ  4384    // 2*DI + 2*N + H (logical)
#define PROJP 4480    // padded to 35*128 for MFMA tiles
#define NLl  12
#define EE   1536

typedef __bf16 bf16x8 __attribute__((ext_vector_type(8)));
typedef float f32x4 __attribute__((ext_vector_type(4)));
typedef unsigned short ushort8 __attribute__((ext_vector_type(8)));

__device__ __forceinline__ unsigned short f2bf(float v) {
  __bf16 b = (__bf16)v;
  return __builtin_bit_cast(unsigned short, b);
}
__device__ __forceinline__ float bf2f(unsigned short u) {
  unsigned int x = ((unsigned int)u) << 16;
  return __builtin_bit_cast(float, x);
}
// split fp32 -> (hi, lo) bf16 pair: v ~= hi + lo to ~16 mantissa bits
__device__ __forceinline__ void split2(float v, unsigned short& h, unsigned short& l) {
  h = f2bf(v);
  l = f2bf(v - bf2f(h));
}

// async global->LDS, 16B per lane (lane-linear LDS layout required)
__device__ __forceinline__ void async16(const void* g, void* l) {
  __builtin_amdgcn_global_load_lds(
      (const __attribute__((address_space(1))) unsigned int*)g,
      (__attribute__((address_space(3))) unsigned int*)l, 16, 0, 0);
}

// ---------------- block reduction helper ----------------
__device__ inline float block_reduce_sum(float v, float* lds) {
#pragma unroll
  for (int d = 32; d > 0; d >>= 1) v += __shfl_down(v, d, 64);
  int lane = threadIdx.x & 63;
  int w = threadIdx.x >> 6;
  if (lane == 0) lds[w] = v;
  __syncthreads();
  if (threadIdx.x == 0) {
    float s = lds[0];
    int nw = blockDim.x >> 6;
    for (int i = 1; i < nw; i++) s += lds[i];
    lds[0] = s;
  }
  __syncthreads();
  return lds[0];
}

// ---------------- fp32 -> bf16 hi/lo (activations, vis+qry fused, row-major) ----------------
__global__ __launch_bounds__(256) void cvt_act_k(const float* __restrict__ vis,
                                                 const float* __restrict__ qry,
                                                 unsigned short* __restrict__ oh,
                                                 unsigned short* __restrict__ ol) {
  int idx = (blockIdx.x * 256 + threadIdx.x) * 8;
  const float* src = (idx < 1024 * 1024) ? &vis[idx] : &qry[idx - 1024 * 1024];
  float4 v0 = *(const float4*)&src[0];
  float4 v1 = *(const float4*)&src[4];
  unsigned short h[8], l[8];
  split2(v0.x, h[0], l[0]); split2(v0.y, h[1], l[1]);
  split2(v0.z, h[2], l[2]); split2(v0.w, h[3], l[3]);
  split2(v1.x, h[4], l[4]); split2(v1.y, h[5], l[5]);
  split2(v1.z, h[6], l[6]); split2(v1.w, h[7], l[7]);
  *(ushort8*)&oh[idx] = *(const ushort8*)h;
  *(ushort8*)&ol[idx] = *(const ushort8*)l;
}

// ---------------- W fp32 [K][N] -> Wt hi/lo bf16 [Npad][K] (transpose+split+pad) ----------------
// Block covers 32 n x 64 k. Store phase: 8 consecutive tids write one row's
// 128B contiguous (16B/thread) -> coalesced; LDS reads spread 2 lanes/bank.
__global__ __launch_bounds__(256) void cvt_tr2_k(const float* __restrict__ W,
                                                 unsigned short* __restrict__ Wth,
                                                 unsigned short* __restrict__ Wtl,
                                                 int K, int N,
                                                 size_t wstride, size_t ostride) {
  __shared__ float tile[64][33];
  W   += (size_t)blockIdx.z * wstride;
  Wth += (size_t)blockIdx.z * ostride;
  Wtl += (size_t)blockIdx.z * ostride;
  const int n0 = blockIdx.x * 32, k0 = blockIdx.y * 64;
  const int c = threadIdx.x & 31;
  const int r0 = threadIdx.x >> 5;   // 0..7
#pragma unroll
  for (int j = 0; j < 8; j++) {
    int r = r0 + j * 8;              // 0..63
    int n = n0 + c;
    tile[r][c] = (n < N) ? W[(size_t)(k0 + r) * N + n] : 0.f;
  }
  __syncthreads();
  const int nl = threadIdx.x >> 3;   // 0..31 (row of output)
  const int kg = threadIdx.x & 7;    // 0..7  (16B chunk within row)
  unsigned short h[8], l[8];
#pragma unroll
  for (int j = 0; j < 8; j++) split2(tile[kg * 8 + j][nl], h[j], l[j]);
  size_t o = (size_t)(n0 + nl) * K + k0 + kg * 8;
  *(ushort8*)&Wth[o] = *(const ushort8*)h;
  *(ushort8*)&Wtl[o] = *(const ushort8*)l;
}

// ---------------- split-bf16 MFMA GEMM, B^T, 3-term (hi*hi + hi*lo + lo*hi) ----------------
// R0-proven structure: 16x16x32 frags, LDS-staged A+B, single buffer.
template<int BM, int BN>
__global__ __launch_bounds__(256) void gemm3_k(
    const unsigned short* __restrict__ Ah, const unsigned short* __restrict__ Al,
    const unsigned short* __restrict__ Wh, const unsigned short* __restrict__ Wl,
    const float* __restrict__ bias, const float* __restrict__ res,
    float* __restrict__ C, int M, int N, int K,
    int rows_per_b, int T_total, int t_off)
{
  constexpr int FM = BM / 32;   // frags per wave (m)
  constexpr int FN = BN / 32;   // frags per wave (n)
  __shared__ __align__(16) unsigned short Ash[BM * 32];
  __shared__ __align__(16) unsigned short Asl[BM * 32];
  __shared__ __align__(16) unsigned short Bsh[BN * 32];
  __shared__ __align__(16) unsigned short Bsl[BN * 32];
  const int tid = threadIdx.x;
  const int lane = tid & 63;
  const int wm = (tid >> 6) >> 1;
  const int wn = (tid >> 6) & 1;
  const int m0 = blockIdx.y * BM;
  const int n0 = blockIdx.x * BN;
  const int lrow = lane & 15;
  const int lkb = (lane >> 4) * 8;   // k-element offset within tile

  f32x4 acc[FM][FN];
#pragma unroll
  for (int i = 0; i < FM; i++)
#pragma unroll
    for (int j = 0; j < FN; j++) acc[i][j] = (f32x4)0.0f;

  for (int k0 = 0; k0 < K; k0 += 32) {
#pragma unroll
    for (int c = 0; c < BM / 64; c++) {
      int o = (c * 256 + tid) * 16;    // byte offset (row-major [BM][32] bf16 = 64B/row)
      int row = o >> 6;
      int colb = o & 63;
      size_t gb = ((size_t)(m0 + row) * K + k0) * 2 + colb;
      async16((const char*)Ah + gb, (char*)Ash + o);
      async16((const char*)Al + gb, (char*)Asl + o);
    }
#pragma unroll
    for (int c = 0; c < BN / 64; c++) {
      int o = (c * 256 + tid) * 16;
      int row = o >> 6;
      int colb = o & 63;
      size_t gb = ((size_t)(n0 + row) * K + k0) * 2 + colb;
      async16((const char*)Wh + gb, (char*)Bsh + o);
      async16((const char*)Wl + gb, (char*)Bsl + o);
    }
    __syncthreads();   // drains vmcnt (global_load_lds) + barrier

    bf16x8 ah[FM], al[FM], bh[FN], bl[FN];
#pragma unroll
    for (int i = 0; i < FM; i++) {
      int off = (wm * (FM * 16) + i * 16 + lrow) * 32 + lkb;
      ah[i] = *(const bf16x8*)&Ash[off];
      al[i] = *(const bf16x8*)&Asl[off];
    }
#pragma unroll
    for (int j = 0; j < FN; j++) {
      int off = (wn * (FN * 16) + j * 16 + lrow) * 32 + lkb;
      bh[j] = *(const bf16x8*)&Bsh[off];
      bl[j] = *(const bf16x8*)&Bsl[off];
    }
#pragma unroll
    for (int i = 0; i < FM; i++)
#pragma unroll
      for (int j = 0; j < FN; j++) {
        acc[i][j] = __builtin_amdgcn_mfma_f32_16x16x32_bf16(ah[i], bh[j], acc[i][j], 0, 0, 0);
        acc[i][j] = __builtin_amdgcn_mfma_f32_16x16x32_bf16(ah[i], bl[j], acc[i][j], 0, 0, 0);
        acc[i][j] = __builtin_amdgcn_mfma_f32_16x16x32_bf16(al[i], bh[j], acc[i][j], 0, 0, 0);
      }
    __syncthreads();
  }

  const int erow = (lane >> 4) * 4;
#pragma unroll
  for (int i = 0; i < FM; i++) {
    int mbase = m0 + wm * (FM * 16) + i * 16 + erow;
#pragma unroll
    for (int j = 0; j < FN; j++) {
      int ncol = n0 + wn * (FN * 16) + j * 16 + lrow;
      float bv = bias ? bias[ncol] : 0.f;
#pragma unroll
      for (int e = 0; e < 4; e++) {
        int m = mbase + e;
        size_t orow;
        if (T_total) {
          int bbv = m / rows_per_b;
          orow = (size_t)bbv * T_total + (m - bbv * rows_per_b) + t_off;
        } else {
          orow = (size_t)m;
        }
        float v = acc[i][j][e] + bv;
        if (res) v += res[orow * N + ncol];
        C[orow * N + ncol] = v;
      }
    }
  }
}

// ---------------- general tiled fp32 GEMM (tiny head matmul only) ----------------
__global__ __launch_bounds__(256) void gemm_k(
    const float* __restrict__ A, const float* __restrict__ W,
    const float* __restrict__ bias, const float* __restrict__ res,
    float* __restrict__ C, int M, int N, int K,
    int rows_per_b, int T_total, int t_off)
{
  __shared__ float As[16][64];
  __shared__ float Ws[16][64];
  const int tid = threadIdx.x;
  const int tx = tid & 15;
  const int ty = tid >> 4;
  const int m0 = blockIdx.y * 64;
  const int n0 = blockIdx.x * 64;
  float acc[4][4] = {};
  const int ar = tid >> 2;
  const int ac = (tid & 3) << 2;
  const int wr = tid >> 4;
  const int wc = (tid & 15) << 2;

  for (int k0 = 0; k0 < K; k0 += 16) {
    float4 av = {0.f, 0.f, 0.f, 0.f};
    int gr = m0 + ar;
    if (gr < M) av = *(const float4*)&A[(size_t)gr * K + k0 + ac];
    As[ac + 0][ar] = av.x; As[ac + 1][ar] = av.y;
    As[ac + 2][ar] = av.z; As[ac + 3][ar] = av.w;

    float4 wv = {0.f, 0.f, 0.f, 0.f};
    int gc = n0 + wc;
    const float* wp = &W[(size_t)(k0 + wr) * N + gc];
    if (gc + 3 < N) {
      wv = *(const float4*)wp;
    } else {
      if (gc + 0 < N) wv.x = wp[0];
      if (gc + 1 < N) wv.y = wp[1];
      if (gc + 2 < N) wv.z = wp[2];
    }
    *(float4*)&Ws[wr][wc] = wv;
    __syncthreads();
#pragma unroll
    for (int kk = 0; kk < 16; kk++) {
      float4 a4 = *(const float4*)&As[kk][ty << 2];
      float4 b4 = *(const float4*)&Ws[kk][tx << 2];
      float a[4] = {a4.x, a4.y, a4.z, a4.w};
      float b[4] = {b4.x, b4.y, b4.z, b4.w};
#pragma unroll
      for (int i = 0; i < 4; i++)
#pragma unroll
        for (int j = 0; j < 4; j++)
          acc[i][j] = fmaf(a[i], b[j], acc[i][j]);
    }
    __syncthreads();
  }
#pragma unroll
  for (int i = 0; i < 4; i++) {
    int gr = m0 + (ty << 2) + i;
    if (gr >= M) continue;
    int bbv = gr / rows_per_b;
    int tt = gr - bbv * rows_per_b;
    size_t orow = (size_t)bbv * T_total + tt + t_off;
#pragma unroll
    for (int j = 0; j < 4; j++) {
      int gc = n0 + (tx << 2) + j;
      if (gc >= N) continue;
      float v = acc[i][j];
      if (bias) v += bias[gc];
      if (res)  v += res[orow * (size_t)N + gc];
      C[orow * (size_t)N + gc] = v;
    }
  }
}

// ---------------- RMSNorm (fp32 out, for final norm) ----------------
__global__ __launch_bounds__(256) void rmsnorm_k(
    const float* __restrict__ x, const float* __restrict__ w, float* __restrict__ out)
{
  __shared__ float lds[8];
  const int row = blockIdx.x;
  const float* xr = x + (size_t)row * Dd;
  float4 v = *(const float4*)&xr[threadIdx.x << 2];
  float ss = v.x * v.x + v.y * v.y + v.z * v.z + v.w * v.w;
  ss = block_reduce_sum(ss, lds);
  float sc = rsqrtf(ss * (1.f / Dd) + 1e-5f);
  float4 wv = *(const float4*)&w[threadIdx.x << 2];
  float4 o = {v.x * sc * wv.x, v.y * sc * wv.y, v.z * sc * wv.z, v.w * sc * wv.w};
  *(float4*)&out[(size_t)row * Dd + (threadIdx.x << 2)] = o;
}

// ---------------- RMSNorm (bf16 hi/lo out, feeds split GEMM) ----------------
__global__ __launch_bounds__(256) void rmsnorm2_k(
    const float* __restrict__ x, const float* __restrict__ w,
    unsigned short* __restrict__ oh, unsigned short* __restrict__ ol)
{
  __shared__ float lds[8];
  const int row = blockIdx.x;
  const float* xr = x + (size_t)row * Dd;
  float4 v = *(const float4*)&xr[threadIdx.x << 2];
  float ss = v.x * v.x + v.y * v.y + v.z * v.z + v.w * v.w;
  ss = block_reduce_sum(ss, lds);
  float sc = rsqrtf(ss * (1.f / Dd) + 1e-5f);
  float4 wv = *(const float4*)&w[threadIdx.x << 2];
  ushort4 h, l;
  split2(v.x * sc * wv.x, h.x, l.x);
  split2(v.y * sc * wv.y, h.y, l.y);
  split2(v.z * sc * wv.z, h.z, l.z);
  split2(v.w * sc * wv.w, h.w, l.w);
  size_t o = (size_t)row * Dd + (threadIdx.x << 2);
  *(ushort4*)&oh[o] = h;
  *(ushort4*)&ol[o] = l;
}

// ---------------- merged: dtcum (y==9) + cbgemm (y<9) ----------------
// Both only READ proj; writes are disjoint -> safe to fuse into one dispatch.
__global__ __launch_bounds__(256) void sscb_k(const float* __restrict__ proj,
                                              const float* __restrict__ dt_bias,
                                              const float* __restrict__ A_log,
                                              float* __restrict__ dtt,
                                              double* __restrict__ dcum,
                                              float* __restrict__ St)
{
  __shared__ float Ct[32][130];
  __shared__ float Bt[32][130];
  if (blockIdx.y == 9) {
    // dt = softplus(.), cum = prefix-sum(dt*A) in fp64; wave per (b,h)
    if (blockIdx.x >= 8) return;
    const int wv = threadIdx.x >> 6;
    const int lane = threadIdx.x & 63;
    const int h = blockIdx.x * 4 + wv;
    const int b = blockIdx.z;
    const float A = -expf(A_log[h]);
    const float bias = dt_bias[h];
    const int rowo = (b * HH + h) * Tt;
    double base = 0.0;
    for (int c = 0; c < (Tt + 63) / 64; c++) {
      int t = c * 64 + lane;
      float dt = 0.f;
      if (t < Tt) {
        float v = proj[(size_t)(b * Tt + t) * PROJP + 2 * DIi + 2 * NNs + h] + bias;
        dt = (v > 20.f) ? v : log1pf(expf(v));
      }
      double a = (double)(dt * A);
#pragma unroll
      for (int d = 1; d < 64; d <<= 1) {
        double o = __shfl_up(a, d, 64);
        if (lane >= d) a += o;
      }
      double cum = base + a;
      if (t < Tt) { dtt[rowo + t] = dt; dcum[rowo + t] = cum; }
      base = __shfl(cum, 63, 64);
    }
    return;
  }
  // St[b][j][t] = B[b,j,:]·C[b,t,:] (32x32 tiles, causal only)
  const int tI = blockIdx.x, jI = blockIdx.y, b = blockIdx.z;
  if (jI > tI) return;
  const int tid = threadIdx.x;
  const int r = tid >> 3;          // 0..31
  const int q = (tid & 7) * 16;    // 16 floats each
  const float* pb = proj + (size_t)b * Tt * PROJP;
  {
    const float* crow = pb + (size_t)(tI * 32 + r) * PROJP + 2 * DIi + NNs + q;
    const float* brow = pb + (size_t)(jI * 32 + r) * PROJP + 2 * DIi + q;
#pragma unroll
    for (int f = 0; f < 16; f += 4) {
      float4 c4 = *(const float4*)&crow[f];
      float4 b4 = *(const float4*)&brow[f];
      *(float2*)&Ct[r][q + f]     = make_float2(c4.x, c4.y);
      *(float2*)&Ct[r][q + f + 2] = make_float2(c4.z, c4.w);
      *(float2*)&Bt[r][q + f]     = make_float2(b4.x, b4.y);
      *(float2*)&Bt[r][q + f + 2] = make_float2(b4.z, b4.w);
    }
  }
  __syncthreads();
  const int j_r = tid >> 3;
  const int t_c = (tid & 7) * 4;
  float acc[4] = {0.f, 0.f, 0.f, 0.f};
  for (int n = 0; n < NNs; n += 2) {
    float2 b2 = *(const float2*)&Bt[j_r][n];
#pragma unroll
    for (int k = 0; k < 4; k++) {
      float2 c2 = *(const float2*)&Ct[t_c + k][n];
      acc[k] = fmaf(b2.x, c2.x, acc[k]);
      acc[k] = fmaf(b2.y, c2.y, acc[k]);
    }
  }
  float* so = St + ((size_t)b * Tt + jI * 32 + j_r) * Tt + tI * 32 + t_c;
  *(float4*)so = make_float4(acc[0], acc[1], acc[2], acc[3]);
}

// ---------------- Y[b,t,h,:] = sum_j M(t,j) * X[b,j,h,:]  (causal, decay-scaled) ----------------
__global__ __launch_bounds__(256) void ssd_y_k(
    const float* __restrict__ proj, const float* __restrict__ St,
    const float* __restrict__ dtt, const double* __restrict__ dcum,
    const float* __restrict__ Dssm, float* __restrict__ ybuf)
{
  const int tI = blockIdx.x;          // 0..8
  const int h  = blockIdx.y;
  const int b  = blockIdx.z;
  __shared__ __align__(16) float Xs[32][64];
  __shared__ __align__(16) float Ss[32][36];   // Ss[j][t], stride 36: conflict-free on t
  __shared__ double cjs[32];
  const int tid = threadIdx.x;
  const int t_l = tid & 31;
  const int pg  = tid >> 5;           // 0..7
  const int t0  = tI * 32;
  const int rowo = (b * HH + h) * Tt;
  const double ct = dcum[rowo + t0 + t_l];
  const float Ds = Dssm[h];
  const float* pb = proj + (size_t)b * Tt * PROJP;
  float y[8] = {0,0,0,0,0,0,0,0};
  const int sr = tid >> 3;            // staging row 0..31
  const int sq = tid & 7;

  for (int jI = 0; jI <= tI; jI++) {
    const int j0 = jI * 32;
    {   // X tile [32 j][64 p] from xss slice
      const float* xr = pb + (size_t)(j0 + sr) * PROJP + DIi + h * PP + sq * 8;
      *(float4*)&Xs[sr][sq * 8]     = *(const float4*)&xr[0];
      *(float4*)&Xs[sr][sq * 8 + 4] = *(const float4*)&xr[4];
    }
    {   // S^T tile scaled by dt_j
      const float* srow = St + ((size_t)b * Tt + j0 + sr) * Tt + t0 + sq * 4;
      float4 s4 = *(const float4*)srow;
      float dj = dtt[rowo + j0 + sr];
      s4.x *= dj; s4.y *= dj; s4.z *= dj; s4.w *= dj;
      *(float4*)&Ss[sr][sq * 4] = s4;
    }
    if (tid < 32) cjs[tid] = dcum[rowo + j0 + tid];
    __syncthreads();

    if (jI < tI) {
#pragma unroll 4
      for (int j = 0; j < 32; j++) {
        float d = (float)(ct - cjs[j]);
        float m = Ss[j][t_l] * expf(fminf(d, 0.f));
        const float* xp = &Xs[j][pg * 8];
        float4 a0 = *(const float4*)&xp[0];
        float4 a1 = *(const float4*)&xp[4];
        y[0] = fmaf(m, a0.x, y[0]); y[1] = fmaf(m, a0.y, y[1]);
        y[2] = fmaf(m, a0.z, y[2]); y[3] = fmaf(m, a0.w, y[3]);
        y[4] = fmaf(m, a1.x, y[4]); y[5] = fmaf(m, a1.y, y[5]);
        y[6] = fmaf(m, a1.z, y[6]); y[7] = fmaf(m, a1.w, y[7]);
      }
    } else {   // diagonal tile: causal mask + diagonal formula
      for (int j = 0; j < 32; j++) {
        float sv = Ss[j][t_l];
        float d = (float)(ct - cjs[j]);
        float m = sv * expf(fminf(d, 0.f));
        if (j == t_l) m = 0.5f * sv + Ds;
        if (j > t_l)  m = 0.f;
        const float* xp = &Xs[j][pg * 8];
        float4 a0 = *(const float4*)&xp[0];
        float4 a1 = *(const float4*)&xp[4];
        y[0] = fmaf(m, a0.x, y[0]); y[1] = fmaf(m, a0.y, y[1]);
        y[2] = fmaf(m, a0.z, y[2]); y[3] = fmaf(m, a0.w, y[3]);
        y[4] = fmaf(m, a1.x, y[4]); y[5] = fmaf(m, a1.y, y[5]);
        y[6] = fmaf(m, a1.z, y[6]); y[7] = fmaf(m, a1.w, y[7]);
      }
    }
    __syncthreads();
  }
  float* yo = &ybuf[(size_t)(b * Tt + t0 + t_l) * DIi + h * PP + pg * 8];
  *(float4*)&yo[0] = make_float4(y[0], y[1], y[2], y[3]);
  *(float4*)&yo[4] = make_float4(y[4], y[5], y[6], y[7]);
}

// ---------------- fused silu-gate + RMSNorm over DI=2048, bf16 hi/lo out ----------------
__global__ __launch_bounds__(256) void gate_norm2_k(
    const float* __restrict__ ybuf, const float* __restrict__ proj,
    const float* __restrict__ gw,
    unsigned short* __restrict__ yh, unsigned short* __restrict__ yl)
{
  __shared__ float lds[8];
  const int row = blockIdx.x;
  const float* yr = ybuf + (size_t)row * DIi;
  const float* zr = proj + (size_t)row * PROJP;   // z = cols [0, 2048)
  const int base = threadIdx.x << 3;
  float4 z0 = *(const float4*)&zr[base];
  float4 z1 = *(const float4*)&zr[base + 4];
  float4 y0 = *(const float4*)&yr[base];
  float4 y1 = *(const float4*)&yr[base + 4];
  float zz[8] = {z0.x, z0.y, z0.z, z0.w, z1.x, z1.y, z1.z, z1.w};
  float yy[8] = {y0.x, y0.y, y0.z, y0.w, y1.x, y1.y, y1.z, y1.w};
  float g[8];
  float ss = 0.f;
#pragma unroll
  for (int e = 0; e < 8; e++) {
    float s = zz[e] / (1.f + expf(-zz[e]));
    float gv = yy[e] * s;
    g[e] = gv;
    ss += gv * gv;
  }
  ss = block_reduce_sum(ss, lds);
  float sc = rsqrtf(ss * (1.f / DIi) + 1e-5f);
  unsigned short h[8], l[8];
#pragma unroll
  for (int e = 0; e < 8; e++) split2(g[e] * sc * gw[base + e], h[e], l[e]);
  size_t o = (size_t)row * DIi + base;
  *(ushort8*)&yh[o] = *(const ushort8*)h;
  *(ushort8*)&yl[o] = *(const ushort8*)l;
}

// ---------------- mean over T ----------------
__global__ void pool_k(const float* __restrict__ xin, float* __restrict__ pooled) {
  int b = blockIdx.x;
  int d = blockIdx.y * 256 + threadIdx.x;
  const float* base = xin + (size_t)b * Tt * Dd + d;
  float s = 0.f;
  for (int t = 0; t < Tt; t++) s += base[(size_t)t * Dd];
  pooled[b * Dd + d] = s * (1.f / Tt);
}

// ---------------- L2-normalize rows of (4, 1536), in place ----------------
__global__ __launch_bounds__(256) void l2norm_k(float* __restrict__ out) {
  __shared__ float lds[8];
  const int row = blockIdx.x;
  float* r = out + (size_t)row * EE;
  float v[6];
  float ss = 0.f;
#pragma unroll
  for (int e = 0; e < 6; e++) {
    v[e] = r[(e << 8) + threadIdx.x];
    ss += v[e] * v[e];
  }
  ss = block_reduce_sum(ss, lds);
  float sc = 1.f / fmaxf(sqrtf(ss), 1e-12f);
#pragma unroll
  for (int e = 0; e < 6; e++) r[(e << 8) + threadIdx.x] = v[e] * sc;
}

// ---------------- launch ----------------
extern "C" void kernel_launch(void* const* d_in, const int* in_sizes, int n_in,
                              void* d_out, int out_size, void* d_ws, size_t ws_size,
                              hipStream_t stream) {
  (void)in_sizes; (void)n_in; (void)out_size;
  const float* visual   = (const float*)d_in[0];
  const float* query    = (const float*)d_in[1];
  const float* vis_w    = (const float*)d_in[2];
  const float* vis_b    = (const float*)d_in[3];
  const float* qry_w    = (const float*)d_in[4];
  const float* qry_b    = (const float*)d_in[5];
  const float* norm_ws  = (const float*)d_in[6];
  const float* in_ws    = (const float*)d_in[7];
  const float* dt_biases= (const float*)d_in[8];
  const float* A_logs   = (const float*)d_in[9];
  const float* D_ssm    = (const float*)d_in[10];
  const float* gnorm_ws = (const float*)d_in[11];
  const float* out_ws   = (const float*)d_in[12];
  const float* norm_f_w = (const float*)d_in[13];
  const float* head_w   = (const float*)d_in[14];
  const float* head_b   = (const float*)d_in[15];
  float* out = (float*)d_out;

  // workspace layout (bytes), all 16B-aligned; base ~69 MB
  char* w = (char*)d_ws;
  float*          hidden = (float*)w;          w += (size_t)1152 * 1024 * 4;
  unsigned short* xh     = (unsigned short*)w; w += (size_t)1152 * 1024 * 2;
  unsigned short* xl     = (unsigned short*)w; w += (size_t)1152 * 1024 * 2;
  float*          proj   = (float*)w;          w += (size_t)1152 * PROJP * 4;
  float*          ybuf   = (float*)w;          w += (size_t)1152 * 2048 * 4;
  unsigned short* yh     = (unsigned short*)w; w += (size_t)1152 * 2048 * 2;
  unsigned short* yl     = (unsigned short*)w; w += (size_t)1152 * 2048 * 2;
  float*          dtt    = (float*)w;          w += (size_t)Bb * HH * Tt * 4;
  double*         dcum   = (double*)w;         w += (size_t)Bb * HH * Tt * 8;
  float*          Stb    = (float*)w;          w += (size_t)Bb * Tt * Tt * 4;
  float*          pooled = (float*)w;          w += (size_t)4096 * 4;
  unsigned short* wth    = (unsigned short*)w; w += (size_t)PROJP * 1024 * 2;
  unsigned short* wtl    = (unsigned short*)w; w += (size_t)PROJP * 1024 * 2;

  // extended region: all-layer pre-converted weights (~330 MB)
  unsigned short* wtin_h  = (unsigned short*)w; w += (size_t)NLl * PROJP * 1024 * 2;
  unsigned short* wtin_l  = (unsigned short*)w; w += (size_t)NLl * PROJP * 1024 * 2;
  unsigned short* wtout_h = (unsigned short*)w; w += (size_t)NLl * 1024 * 2048 * 2;
  unsigned short* wtout_l = (unsigned short*)w; w += (size_t)NLl * 1024 * 2048 * 2;
  unsigned short* wtv_h   = (unsigned short*)w; w += (size_t)1024 * 1024 * 2;
  unsigned short* wtv_l   = (unsigned short*)w; w += (size_t)1024 * 1024 * 2;
  unsigned short* wtq_h   = (unsigned short*)w; w += (size_t)1024 * 1024 * 2;
  unsigned short* wtq_l   = (unsigned short*)w; w += (size_t)1024 * 1024 * 2;
  const bool batched = ((size_t)(w - (char*)d_ws)) <= ws_size;

  dim3 blk(256);

  // ---- activations -> split bf16 (vis+qry in one launch) ----
  cvt_act_k<<<576, blk, 0, stream>>>(visual, query, xh, xl);

  if (batched) {
    // ---- all weight conversions upfront (4 launches instead of 24 in-loop) ----
    cvt_tr2_k<<<dim3(32, 16, 1), blk, 0, stream>>>(vis_w, wtv_h, wtv_l, 1024, 1024, 0, 0);
    cvt_tr2_k<<<dim3(32, 16, 1), blk, 0, stream>>>(qry_w, wtq_h, wtq_l, 1024, 1024, 0, 0);
    cvt_tr2_k<<<dim3(PROJP / 32, 16, NLl), blk, 0, stream>>>(
        in_ws, wtin_h, wtin_l, Dd, PROJ, (size_t)Dd * PROJ, (size_t)PROJP * 1024);
    cvt_tr2_k<<<dim3(32, 32, NLl), blk, 0, stream>>>(
        out_ws, wtout_h, wtout_l, DIi, Dd, (size_t)DIi * Dd, (size_t)1024 * 2048);
    gemm3_k<64, 64><<<dim3(16, 16), blk, 0, stream>>>(
        xh, xl, wtv_h, wtv_l, vis_b, nullptr, hidden, 1024, 1024, 1024, 256, Tt, 0);
    gemm3_k<64, 64><<<dim3(16, 2), blk, 0, stream>>>(
        xh + (size_t)1024 * 1024, xl + (size_t)1024 * 1024, wtq_h, wtq_l,
        qry_b, nullptr, hidden, 128, 1024, 1024, 32, Tt, 256);
  } else {
    cvt_tr2_k<<<dim3(32, 16, 1), blk, 0, stream>>>(vis_w, wth, wtl, 1024, 1024, 0, 0);
    gemm3_k<64, 64><<<dim3(16, 16), blk, 0, stream>>>(
        xh, xl, wth, wtl, vis_b, nullptr, hidden, 1024, 1024, 1024, 256, Tt, 0);
    cvt_tr2_k<<<dim3(32, 16, 1), blk, 0, stream>>>(qry_w, wth, wtl, 1024, 1024, 0, 0);
    gemm3_k<64, 64><<<dim3(16, 2), blk, 0, stream>>>(
        xh + (size_t)1024 * 1024, xl + (size_t)1024 * 1024, wth, wtl,
        qry_b, nullptr, hidden, 128, 1024, 1024, 32, Tt, 256);
  }

  for (int i = 0; i < NLl; i++) {
    rmsnorm2_k<<<Bb * Tt, blk, 0, stream>>>(hidden, norm_ws + i * Dd, xh, xl);
    // in-proj: W [1024][4384] -> Wt [4480][1024]; C = proj [1152][4480]
    const unsigned short *bih, *bil;
    if (batched) {
      bih = wtin_h + (size_t)i * PROJP * 1024;
      bil = wtin_l + (size_t)i * PROJP * 1024;
    } else {
      cvt_tr2_k<<<dim3(PROJP / 32, 16, 1), blk, 0, stream>>>(
          in_ws + (size_t)i * Dd * PROJ, wth, wtl, Dd, PROJ, 0, 0);
      bih = wth; bil = wtl;
    }
    gemm3_k<128, 128><<<dim3(PROJP / 128, 9), blk, 0, stream>>>(
        xh, xl, bih, bil, nullptr, nullptr, proj, 1152, PROJP, Dd, 1152, 0, 0);
    // SSD quadratic form: merged dtcum + cbgemm, then ssd_y
    sscb_k<<<dim3(9, 10, Bb), blk, 0, stream>>>(proj, dt_biases + i * HH,
                                                A_logs + i * HH, dtt, dcum, Stb);
    ssd_y_k<<<dim3(9, HH, Bb), blk, 0, stream>>>(proj, Stb, dtt, dcum,
                                                 D_ssm + i * HH, ybuf);
    gate_norm2_k<<<Bb * Tt, blk, 0, stream>>>(ybuf, proj, gnorm_ws + i * DIi, yh, yl);
    // out-proj: W [2048][1024] -> Wt [1024][2048]; C = hidden (+res)
    const unsigned short *boh, *bol;
    if (batched) {
      boh = wtout_h + (size_t)i * 1024 * 2048;
      bol = wtout_l + (size_t)i * 1024 * 2048;
    } else {
      cvt_tr2_k<<<dim3(32, 32, 1), blk, 0, stream>>>(
          out_ws + (size_t)i * DIi * Dd, wth, wtl, DIi, Dd, 0, 0);
      boh = wth; bol = wtl;
    }
    gemm3_k<64, 64><<<dim3(16, 18), blk, 0, stream>>>(
        yh, yl, boh, bol, nullptr, hidden, hidden, 1152, Dd, DIi, 1152, 0, 0);
  }

  rmsnorm_k<<<Bb * Tt, blk, 0, stream>>>(hidden, norm_f_w, ybuf);
  pool_k<<<dim3(Bb, 4), blk, 0, stream>>>(ybuf, pooled);
  gemm_k<<<dim3(24, 1), blk, 0, stream>>>(pooled, head_w, head_b, nullptr, out,
                                          Bb, EE, Dd, Bb, 0, 0);
  l2norm_k<<<Bb, blk, 0, stream>>>(out);
}

// Round 5
// 2684.570 us; speedup vs baseline: 1.1598x; 1.0199x over previous
//
#include <hip/hip_runtime.h>
#include <cmath>

// Shapes (fixed by the problem)
#define Bb   4
#define Tt   288      // NV(256) + NQ(32)
#define Dd   1024
#define DIi  2048
#define HH   32
#define PP   64
#define NNs  128
#define PROJ  4384    // 2*DI + 2*N + H (logical)
#define PROJP 4480    // padded to 35*128 for MFMA tiles
#define NLl  12
#define EE   1536

typedef __bf16 bf16x8 __attribute__((ext_vector_type(8)));
typedef float f32x4 __attribute__((ext_vector_type(4)));
typedef unsigned short ushort8 __attribute__((ext_vector_type(8)));

__device__ __forceinline__ unsigned short f2bf(float v) {
  __bf16 b = (__bf16)v;
  return __builtin_bit_cast(unsigned short, b);
}
__device__ __forceinline__ float bf2f(unsigned short u) {
  unsigned int x = ((unsigned int)u) << 16;
  return __builtin_bit_cast(float, x);
}
// split fp32 -> (hi, lo) bf16 pair: v ~= hi + lo to ~16 mantissa bits
__device__ __forceinline__ void split2(float v, unsigned short& h, unsigned short& l) {
  h = f2bf(v);
  l = f2bf(v - bf2f(h));
}

// async global->LDS, 16B per lane (lane-linear LDS layout required)
__device__ __forceinline__ void async16(const void* g, void* l) {
  __builtin_amdgcn_global_load_lds(
      (const __attribute__((address_space(1))) unsigned int*)g,
      (__attribute__((address_space(3))) unsigned int*)l, 16, 0, 0);
}

// ---------------- block reduction helper ----------------
__device__ inline float block_reduce_sum(float v, float* lds) {
#pragma unroll
  for (int d = 32; d > 0; d >>= 1) v += __shfl_down(v, d, 64);
  int lane = threadIdx.x & 63;
  int w = threadIdx.x >> 6;
  if (lane == 0) lds[w] = v;
  __syncthreads();
  if (threadIdx.x == 0) {
    float s = lds[0];
    int nw = blockDim.x >> 6;
    for (int i = 1; i < nw; i++) s += lds[i];
    lds[0] = s;
  }
  __syncthreads();
  return lds[0];
}

// ---------------- fp32 -> bf16 hi/lo (activations, vis+qry fused, row-major) ----------------
__global__ __launch_bounds__(256) void cvt_act_k(const float* __restrict__ vis,
                                                 const float* __restrict__ qry,
                                                 unsigned short* __restrict__ oh,
                                                 unsigned short* __restrict__ ol) {
  int idx = (blockIdx.x * 256 + threadIdx.x) * 8;
  const float* src = (idx < 1024 * 1024) ? &vis[idx] : &qry[idx - 1024 * 1024];
  float4 v0 = *(const float4*)&src[0];
  float4 v1 = *(const float4*)&src[4];
  unsigned short h[8], l[8];
  split2(v0.x, h[0], l[0]); split2(v0.y, h[1], l[1]);
  split2(v0.z, h[2], l[2]); split2(v0.w, h[3], l[3]);
  split2(v1.x, h[4], l[4]); split2(v1.y, h[5], l[5]);
  split2(v1.z, h[6], l[6]); split2(v1.w, h[7], l[7]);
  *(ushort8*)&oh[idx] = *(const ushort8*)h;
  *(ushort8*)&ol[idx] = *(const ushort8*)l;
}

// ---------------- W fp32 [K][N] -> Wt hi/lo bf16 [Npad][K] (transpose+split+pad) ----------------
// Block covers 32 n x 64 k. Store phase: 8 consecutive tids write one row's
// 128B contiguous (16B/thread) -> coalesced. W2: optional second source for z==1.
__global__ __launch_bounds__(256) void cvt_tr2_k(const float* __restrict__ W,
                                                 unsigned short* __restrict__ Wth,
                                                 unsigned short* __restrict__ Wtl,
                                                 int K, int N,
                                                 size_t wstride, size_t ostride,
                                                 const float* __restrict__ W2) {
  __shared__ float tile[64][33];
  const float* Wp = (blockIdx.z == 1 && W2) ? W2 : W + (size_t)blockIdx.z * wstride;
  Wth += (size_t)blockIdx.z * ostride;
  Wtl += (size_t)blockIdx.z * ostride;
  const int n0 = blockIdx.x * 32, k0 = blockIdx.y * 64;
  const int c = threadIdx.x & 31;
  const int r0 = threadIdx.x >> 5;   // 0..7
#pragma unroll
  for (int j = 0; j < 8; j++) {
    int r = r0 + j * 8;              // 0..63
    int n = n0 + c;
    tile[r][c] = (n < N) ? Wp[(size_t)(k0 + r) * N + n] : 0.f;
  }
  __syncthreads();
  const int nl = threadIdx.x >> 3;   // 0..31 (row of output)
  const int kg = threadIdx.x & 7;    // 0..7  (16B chunk within row)
  unsigned short h[8], l[8];
#pragma unroll
  for (int j = 0; j < 8; j++) split2(tile[kg * 8 + j][nl], h[j], l[j]);
  size_t o = (size_t)(n0 + nl) * K + k0 + kg * 8;
  *(ushort8*)&Wth[o] = *(const ushort8*)h;
  *(ushort8*)&Wtl[o] = *(const ushort8*)l;
}

// ---------------- split-bf16 MFMA GEMM, B^T, 3-term (hi*hi + hi*lo + lo*hi) ----------------
// 16x16x32 frags (R4-proven). DBUF: double-buffered LDS, stage(next) issued
// BEFORE compute(cur), ONE barrier per k-step (guide T3-minimal 2-phase).
// Region-2 params (Wh2/...): rows m >= m_split use the second weight/bias and
// row-mapping — used to merge the vis+qry init GEMMs into one dispatch.
template<int BM, int BN, bool DBUF>
__global__ __launch_bounds__(256) void gemm3_k(
    const unsigned short* __restrict__ Ah, const unsigned short* __restrict__ Al,
    const unsigned short* __restrict__ Wh, const unsigned short* __restrict__ Wl,
    const float* __restrict__ bias, const float* __restrict__ res,
    float* __restrict__ C, int M, int N, int K,
    int rows_per_b, int T_total, int t_off,
    const unsigned short* __restrict__ Wh2, const unsigned short* __restrict__ Wl2,
    const float* __restrict__ bias2, int m_split, int rows_per_b2, int t_off2)
{
  constexpr int FM = BM / 32;   // frags per wave (m)
  constexpr int FN = BN / 32;   // frags per wave (n)
  constexpr int NB = DBUF ? 2 : 1;
  __shared__ __align__(16) unsigned short Ash[NB][BM * 32];
  __shared__ __align__(16) unsigned short Asl[NB][BM * 32];
  __shared__ __align__(16) unsigned short Bsh[NB][BN * 32];
  __shared__ __align__(16) unsigned short Bsl[NB][BN * 32];
  const int tid = threadIdx.x;
  const int lane = tid & 63;
  const int wm = (tid >> 6) >> 1;
  const int wn = (tid >> 6) & 1;
  const int m0 = blockIdx.y * BM;
  const int n0 = blockIdx.x * BN;
  const bool reg2 = (m0 >= m_split);
  const unsigned short* WhS = reg2 ? Wh2 : Wh;
  const unsigned short* WlS = reg2 ? Wl2 : Wl;
  const int lrow = lane & 15;
  const int lkb = (lane >> 4) * 8;   // k-element offset within tile

  f32x4 acc[FM][FN];
#pragma unroll
  for (int i = 0; i < FM; i++)
#pragma unroll
    for (int j = 0; j < FN; j++) acc[i][j] = (f32x4)0.0f;

  auto stage = [&](int bf, int k0) {
#pragma unroll
    for (int c = 0; c < BM / 64; c++) {
      int o = (c * 256 + tid) * 16;    // byte offset (row-major [BM][32] bf16 = 64B/row)
      int row = o >> 6;
      int colb = o & 63;
      size_t gb = ((size_t)(m0 + row) * K + k0) * 2 + colb;
      async16((const char*)Ah + gb, (char*)Ash[bf] + o);
      async16((const char*)Al + gb, (char*)Asl[bf] + o);
    }
#pragma unroll
    for (int c = 0; c < BN / 64; c++) {
      int o = (c * 256 + tid) * 16;
      int row = o >> 6;
      int colb = o & 63;
      size_t gb = ((size_t)(n0 + row) * K + k0) * 2 + colb;
      async16((const char*)WhS + gb, (char*)Bsh[bf] + o);
      async16((const char*)WlS + gb, (char*)Bsl[bf] + o);
    }
  };

  auto compute = [&](int bf) {
    bf16x8 ah[FM], al[FM], bh[FN], bl[FN];
#pragma unroll
    for (int i = 0; i < FM; i++) {
      int off = (wm * (FM * 16) + i * 16 + lrow) * 32 + lkb;
      ah[i] = *(const bf16x8*)&Ash[bf][off];
      al[i] = *(const bf16x8*)&Asl[bf][off];
    }
#pragma unroll
    for (int j = 0; j < FN; j++) {
      int off = (wn * (FN * 16) + j * 16 + lrow) * 32 + lkb;
      bh[j] = *(const bf16x8*)&Bsh[bf][off];
      bl[j] = *(const bf16x8*)&Bsl[bf][off];
    }
#pragma unroll
    for (int i = 0; i < FM; i++)
#pragma unroll
      for (int j = 0; j < FN; j++) {
        acc[i][j] = __builtin_amdgcn_mfma_f32_16x16x32_bf16(ah[i], bh[j], acc[i][j], 0, 0, 0);
        acc[i][j] = __builtin_amdgcn_mfma_f32_16x16x32_bf16(ah[i], bl[j], acc[i][j], 0, 0, 0);
        acc[i][j] = __builtin_amdgcn_mfma_f32_16x16x32_bf16(al[i], bh[j], acc[i][j], 0, 0, 0);
      }
  };

  if (DBUF) {
    stage(0, 0);
    __syncthreads();
    int cur = 0;
    for (int k0 = 0; k0 < K; k0 += 32) {
      if (k0 + 32 < K) stage(cur ^ 1, k0 + 32);   // async into other buffer
      compute(cur);
      __syncthreads();   // drains next-buffer loads; protects cur for overwrite
      cur ^= 1;
    }
  } else {
    for (int k0 = 0; k0 < K; k0 += 32) {
      stage(0, k0);
      __syncthreads();
      compute(0);
      __syncthreads();
    }
  }

  const float* BI = reg2 ? bias2 : bias;
  const int rpb  = reg2 ? rows_per_b2 : rows_per_b;
  const int tof  = reg2 ? t_off2 : t_off;
  const int msub = reg2 ? m_split : 0;
  const int erow = (lane >> 4) * 4;
#pragma unroll
  for (int i = 0; i < FM; i++) {
    int mbase = m0 + wm * (FM * 16) + i * 16 + erow;
#pragma unroll
    for (int j = 0; j < FN; j++) {
      int ncol = n0 + wn * (FN * 16) + j * 16 + lrow;
      float bv = BI ? BI[ncol] : 0.f;
#pragma unroll
      for (int e = 0; e < 4; e++) {
        int m = mbase + e;
        int mm = m - msub;
        size_t orow;
        if (T_total) {
          int bbv = mm / rpb;
          orow = (size_t)bbv * T_total + (mm - bbv * rpb) + tof;
        } else {
          orow = (size_t)m;
        }
        float v = acc[i][j][e] + bv;
        if (res) v += res[orow * N + ncol];
        C[orow * N + ncol] = v;
      }
    }
  }
}

// ---------------- general tiled fp32 GEMM (tiny head matmul only) ----------------
__global__ __launch_bounds__(256) void gemm_k(
    const float* __restrict__ A, const float* __restrict__ W,
    const float* __restrict__ bias, const float* __restrict__ res,
    float* __restrict__ C, int M, int N, int K,
    int rows_per_b, int T_total, int t_off)
{
  __shared__ float As[16][64];
  __shared__ float Ws[16][64];
  const int tid = threadIdx.x;
  const int tx = tid & 15;
  const int ty = tid >> 4;
  const int m0 = blockIdx.y * 64;
  const int n0 = blockIdx.x * 64;
  float acc[4][4] = {};
  const int ar = tid >> 2;
  const int ac = (tid & 3) << 2;
  const int wr = tid >> 4;
  const int wc = (tid & 15) << 2;

  for (int k0 = 0; k0 < K; k0 += 16) {
    float4 av = {0.f, 0.f, 0.f, 0.f};
    int gr = m0 + ar;
    if (gr < M) av = *(const float4*)&A[(size_t)gr * K + k0 + ac];
    As[ac + 0][ar] = av.x; As[ac + 1][ar] = av.y;
    As[ac + 2][ar] = av.z; As[ac + 3][ar] = av.w;

    float4 wv = {0.f, 0.f, 0.f, 0.f};
    int gc = n0 + wc;
    const float* wp = &W[(size_t)(k0 + wr) * N + gc];
    if (gc + 3 < N) {
      wv = *(const float4*)wp;
    } else {
      if (gc + 0 < N) wv.x = wp[0];
      if (gc + 1 < N) wv.y = wp[1];
      if (gc + 2 < N) wv.z = wp[2];
    }
    *(float4*)&Ws[wr][wc] = wv;
    __syncthreads();
#pragma unroll
    for (int kk = 0; kk < 16; kk++) {
      float4 a4 = *(const float4*)&As[kk][ty << 2];
      float4 b4 = *(const float4*)&Ws[kk][tx << 2];
      float a[4] = {a4.x, a4.y, a4.z, a4.w};
      float b[4] = {b4.x, b4.y, b4.z, b4.w};
#pragma unroll
      for (int i = 0; i < 4; i++)
#pragma unroll
        for (int j = 0; j < 4; j++)
          acc[i][j] = fmaf(a[i], b[j], acc[i][j]);
    }
    __syncthreads();
  }
#pragma unroll
  for (int i = 0; i < 4; i++) {
    int gr = m0 + (ty << 2) + i;
    if (gr >= M) continue;
    int bbv = gr / rows_per_b;
    int tt = gr - bbv * rows_per_b;
    size_t orow = (size_t)bbv * T_total + tt + t_off;
#pragma unroll
    for (int j = 0; j < 4; j++) {
      int gc = n0 + (tx << 2) + j;
      if (gc >= N) continue;
      float v = acc[i][j];
      if (bias) v += bias[gc];
      if (res)  v += res[orow * (size_t)N + gc];
      C[orow * (size_t)N + gc] = v;
    }
  }
}

// ---------------- RMSNorm (fp32 out, for final norm) ----------------
__global__ __launch_bounds__(256) void rmsnorm_k(
    const float* __restrict__ x, const float* __restrict__ w, float* __restrict__ out)
{
  __shared__ float lds[8];
  const int row = blockIdx.x;
  const float* xr = x + (size_t)row * Dd;
  float4 v = *(const float4*)&xr[threadIdx.x << 2];
  float ss = v.x * v.x + v.y * v.y + v.z * v.z + v.w * v.w;
  ss = block_reduce_sum(ss, lds);
  float sc = rsqrtf(ss * (1.f / Dd) + 1e-5f);
  float4 wv = *(const float4*)&w[threadIdx.x << 2];
  float4 o = {v.x * sc * wv.x, v.y * sc * wv.y, v.z * sc * wv.z, v.w * sc * wv.w};
  *(float4*)&out[(size_t)row * Dd + (threadIdx.x << 2)] = o;
}

// ---------------- RMSNorm (bf16 hi/lo out, feeds split GEMM) ----------------
__global__ __launch_bounds__(256) void rmsnorm2_k(
    const float* __restrict__ x, const float* __restrict__ w,
    unsigned short* __restrict__ oh, unsigned short* __restrict__ ol)
{
  __shared__ float lds[8];
  const int row = blockIdx.x;
  const float* xr = x + (size_t)row * Dd;
  float4 v = *(const float4*)&xr[threadIdx.x << 2];
  float ss = v.x * v.x + v.y * v.y + v.z * v.z + v.w * v.w;
  ss = block_reduce_sum(ss, lds);
  float sc = rsqrtf(ss * (1.f / Dd) + 1e-5f);
  float4 wv = *(const float4*)&w[threadIdx.x << 2];
  ushort4 h, l;
  split2(v.x * sc * wv.x, h.x, l.x);
  split2(v.y * sc * wv.y, h.y, l.y);
  split2(v.z * sc * wv.z, h.z, l.z);
  split2(v.w * sc * wv.w, h.w, l.w);
  size_t o = (size_t)row * Dd + (threadIdx.x << 2);
  *(ushort4*)&oh[o] = h;
  *(ushort4*)&ol[o] = l;
}

// ---------------- merged: dtcum (y==9) + cbgemm (y<9) ----------------
// Both only READ proj; writes are disjoint -> safe to fuse into one dispatch.
__global__ __launch_bounds__(256) void sscb_k(const float* __restrict__ proj,
                                              const float* __restrict__ dt_bias,
                                              const float* __restrict__ A_log,
                                              float* __restrict__ dtt,
                                              double* __restrict__ dcum,
                                              float* __restrict__ St)
{
  __shared__ float Ct[32][130];
  __shared__ float Bt[32][130];
  if (blockIdx.y == 9) {
    // dt = softplus(.), cum = prefix-sum(dt*A) in fp64; wave per (b,h)
    if (blockIdx.x >= 8) return;
    const int wv = threadIdx.x >> 6;
    const int lane = threadIdx.x & 63;
    const int h = blockIdx.x * 4 + wv;
    const int b = blockIdx.z;
    const float A = -expf(A_log[h]);
    const float bias = dt_bias[h];
    const int rowo = (b * HH + h) * Tt;
    double base = 0.0;
    for (int c = 0; c < (Tt + 63) / 64; c++) {
      int t = c * 64 + lane;
      float dt = 0.f;
      if (t < Tt) {
        float v = proj[(size_t)(b * Tt + t) * PROJP + 2 * DIi + 2 * NNs + h] + bias;
        dt = (v > 20.f) ? v : log1pf(expf(v));
      }
      double a = (double)(dt * A);
#pragma unroll
      for (int d = 1; d < 64; d <<= 1) {
        double o = __shfl_up(a, d, 64);
        if (lane >= d) a += o;
      }
      double cum = base + a;
      if (t < Tt) { dtt[rowo + t] = dt; dcum[rowo + t] = cum; }
      base = __shfl(cum, 63, 64);
    }
    return;
  }
  // St[b][j][t] = B[b,j,:]·C[b,t,:] (32x32 tiles, causal only)
  const int tI = blockIdx.x, jI = blockIdx.y, b = blockIdx.z;
  if (jI > tI) return;
  const int tid = threadIdx.x;
  const int r = tid >> 3;          // 0..31
  const int q = (tid & 7) * 16;    // 16 floats each
  const float* pb = proj + (size_t)b * Tt * PROJP;
  {
    const float* crow = pb + (size_t)(tI * 32 + r) * PROJP + 2 * DIi + NNs + q;
    const float* brow = pb + (size_t)(jI * 32 + r) * PROJP + 2 * DIi + q;
#pragma unroll
    for (int f = 0; f < 16; f += 4) {
      float4 c4 = *(const float4*)&crow[f];
      float4 b4 = *(const float4*)&brow[f];
      *(float2*)&Ct[r][q + f]     = make_float2(c4.x, c4.y);
      *(float2*)&Ct[r][q + f + 2] = make_float2(c4.z, c4.w);
      *(float2*)&Bt[r][q + f]     = make_float2(b4.x, b4.y);
      *(float2*)&Bt[r][q + f + 2] = make_float2(b4.z, b4.w);
    }
  }
  __syncthreads();
  const int j_r = tid >> 3;
  const int t_c = (tid & 7) * 4;
  float acc[4] = {0.f, 0.f, 0.f, 0.f};
  for (int n = 0; n < NNs; n += 2) {
    float2 b2 = *(const float2*)&Bt[j_r][n];
#pragma unroll
    for (int k = 0; k < 4; k++) {
      float2 c2 = *(const float2*)&Ct[t_c + k][n];
      acc[k] = fmaf(b2.x, c2.x, acc[k]);
      acc[k] = fmaf(b2.y, c2.y, acc[k]);
    }
  }
  float* so = St + ((size_t)b * Tt + jI * 32 + j_r) * Tt + tI * 32 + t_c;
  *(float4*)so = make_float4(acc[0], acc[1], acc[2], acc[3]);
}

// ---------------- Y[b,t,h,:] = sum_j M(t,j) * X[b,j,h,:]  (causal, decay-scaled) ----------------
__global__ __launch_bounds__(256) void ssd_y_k(
    const float* __restrict__ proj, const float* __restrict__ St,
    const float* __restrict__ dtt, const double* __restrict__ dcum,
    const float* __restrict__ Dssm, float* __restrict__ ybuf)
{
  const int tI = blockIdx.x;          // 0..8
  const int h  = blockIdx.y;
  const int b  = blockIdx.z;
  __shared__ __align__(16) float Xs[32][64];
  __shared__ __align__(16) float Ss[32][36];   // Ss[j][t], stride 36: conflict-free on t
  __shared__ double cjs[32];
  const int tid = threadIdx.x;
  const int t_l = tid & 31;
  const int pg  = tid >> 5;           // 0..7
  const int t0  = tI * 32;
  const int rowo = (b * HH + h) * Tt;
  const double ct = dcum[rowo + t0 + t_l];
  const float Ds = Dssm[h];
  const float* pb = proj + (size_t)b * Tt * PROJP;
  float y[8] = {0,0,0,0,0,0,0,0};
  const int sr = tid >> 3;            // staging row 0..31
  const int sq = tid & 7;

  for (int jI = 0; jI <= tI; jI++) {
    const int j0 = jI * 32;
    {   // X tile [32 j][64 p] from xss slice
      const float* xr = pb + (size_t)(j0 + sr) * PROJP + DIi + h * PP + sq * 8;
      *(float4*)&Xs[sr][sq * 8]     = *(const float4*)&xr[0];
      *(float4*)&Xs[sr][sq * 8 + 4] = *(const float4*)&xr[4];
    }
    {   // S^T tile scaled by dt_j
      const float* srow = St + ((size_t)b * Tt + j0 + sr) * Tt + t0 + sq * 4;
      float4 s4 = *(const float4*)srow;
      float dj = dtt[rowo + j0 + sr];
      s4.x *= dj; s4.y *= dj; s4.z *= dj; s4.w *= dj;
      *(float4*)&Ss[sr][sq * 4] = s4;
    }
    if (tid < 32) cjs[tid] = dcum[rowo + j0 + tid];
    __syncthreads();

    if (jI < tI) {
#pragma unroll 4
      for (int j = 0; j < 32; j++) {
        float d = (float)(ct - cjs[j]);
        float m = Ss[j][t_l] * expf(fminf(d, 0.f));
        const float* xp = &Xs[j][pg * 8];
        float4 a0 = *(const float4*)&xp[0];
        float4 a1 = *(const float4*)&xp[4];
        y[0] = fmaf(m, a0.x, y[0]); y[1] = fmaf(m, a0.y, y[1]);
        y[2] = fmaf(m, a0.z, y[2]); y[3] = fmaf(m, a0.w, y[3]);
        y[4] = fmaf(m, a1.x, y[4]); y[5] = fmaf(m, a1.y, y[5]);
        y[6] = fmaf(m, a1.z, y[6]); y[7] = fmaf(m, a1.w, y[7]);
      }
    } else {   // diagonal tile: causal mask + diagonal formula
      for (int j = 0; j < 32; j++) {
        float sv = Ss[j][t_l];
        float d = (float)(ct - cjs[j]);
        float m = sv * expf(fminf(d, 0.f));
        if (j == t_l) m = 0.5f * sv + Ds;
        if (j > t_l)  m = 0.f;
        const float* xp = &Xs[j][pg * 8];
        float4 a0 = *(const float4*)&xp[0];
        float4 a1 = *(const float4*)&xp[4];
        y[0] = fmaf(m, a0.x, y[0]); y[1] = fmaf(m, a0.y, y[1]);
        y[2] = fmaf(m, a0.z, y[2]); y[3] = fmaf(m, a0.w, y[3]);
        y[4] = fmaf(m, a1.x, y[4]); y[5] = fmaf(m, a1.y, y[5]);
        y[6] = fmaf(m, a1.z, y[6]); y[7] = fmaf(m, a1.w, y[7]);
      }
    }
    __syncthreads();
  }
  float* yo = &ybuf[(size_t)(b * Tt + t0 + t_l) * DIi + h * PP + pg * 8];
  *(float4*)&yo[0] = make_float4(y[0], y[1], y[2], y[3]);
  *(float4*)&yo[4] = make_float4(y[4], y[5], y[6], y[7]);
}

// ---------------- fused silu-gate + RMSNorm over DI=2048, bf16 hi/lo out ----------------
__global__ __launch_bounds__(256) void gate_norm2_k(
    const float* __restrict__ ybuf, const float* __restrict__ proj,
    const float* __restrict__ gw,
    unsigned short* __restrict__ yh, unsigned short* __restrict__ yl)
{
  __shared__ float lds[8];
  const int row = blockIdx.x;
  const float* yr = ybuf + (size_t)row * DIi;
  const float* zr = proj + (size_t)row * PROJP;   // z = cols [0, 2048)
  const int base = threadIdx.x << 3;
  float4 z0 = *(const float4*)&zr[base];
  float4 z1 = *(const float4*)&zr[base + 4];
  float4 y0 = *(const float4*)&yr[base];
  float4 y1 = *(const float4*)&yr[base + 4];
  float zz[8] = {z0.x, z0.y, z0.z, z0.w, z1.x, z1.y, z1.z, z1.w};
  float yy[8] = {y0.x, y0.y, y0.z, y0.w, y1.x, y1.y, y1.z, y1.w};
  float g[8];
  float ss = 0.f;
#pragma unroll
  for (int e = 0; e < 8; e++) {
    float s = zz[e] / (1.f + expf(-zz[e]));
    float gv = yy[e] * s;
    g[e] = gv;
    ss += gv * gv;
  }
  ss = block_reduce_sum(ss, lds);
  float sc = rsqrtf(ss * (1.f / DIi) + 1e-5f);
  unsigned short h[8], l[8];
#pragma unroll
  for (int e = 0; e < 8; e++) split2(g[e] * sc * gw[base + e], h[e], l[e]);
  size_t o = (size_t)row * DIi + base;
  *(ushort8*)&yh[o] = *(const ushort8*)h;
  *(ushort8*)&yl[o] = *(const ushort8*)l;
}

// ---------------- mean over T ----------------
__global__ void pool_k(const float* __restrict__ xin, float* __restrict__ pooled) {
  int b = blockIdx.x;
  int d = blockIdx.y * 256 + threadIdx.x;
  const float* base = xin + (size_t)b * Tt * Dd + d;
  float s = 0.f;
  for (int t = 0; t < Tt; t++) s += base[(size_t)t * Dd];
  pooled[b * Dd + d] = s * (1.f / Tt);
}

// ---------------- L2-normalize rows of (4, 1536), in place ----------------
__global__ __launch_bounds__(256) void l2norm_k(float* __restrict__ out) {
  __shared__ float lds[8];
  const int row = blockIdx.x;
  float* r = out + (size_t)row * EE;
  float v[6];
  float ss = 0.f;
#pragma unroll
  for (int e = 0; e < 6; e++) {
    v[e] = r[(e << 8) + threadIdx.x];
    ss += v[e] * v[e];
  }
  ss = block_reduce_sum(ss, lds);
  float sc = 1.f / fmaxf(sqrtf(ss), 1e-12f);
#pragma unroll
  for (int e = 0; e < 6; e++) r[(e << 8) + threadIdx.x] = v[e] * sc;
}

// ---------------- launch ----------------
extern "C" void kernel_launch(void* const* d_in, const int* in_sizes, int n_in,
                              void* d_out, int out_size, void* d_ws, size_t ws_size,
                              hipStream_t stream) {
  (void)in_sizes; (void)n_in; (void)out_size;
  const float* visual   = (const float*)d_in[0];
  const float* query    = (const float*)d_in[1];
  const float* vis_w    = (const float*)d_in[2];
  const float* vis_b    = (const float*)d_in[3];
  const float* qry_w    = (const float*)d_in[4];
  const float* qry_b    = (const float*)d_in[5];
  const float* norm_ws  = (const float*)d_in[6];
  const float* in_ws    = (const float*)d_in[7];
  const float* dt_biases= (const float*)d_in[8];
  const float* A_logs   = (const float*)d_in[9];
  const float* D_ssm    = (const float*)d_in[10];
  const float* gnorm_ws = (const float*)d_in[11];
  const float* out_ws   = (const float*)d_in[12];
  const float* norm_f_w = (const float*)d_in[13];
  const float* head_w   = (const float*)d_in[14];
  const float* head_b   = (const float*)d_in[15];
  float* out = (float*)d_out;
  const int NONE = 0x7fffffff;

  // workspace layout (bytes), all 16B-aligned; base ~69 MB
  char* w = (char*)d_ws;
  float*          hidden = (float*)w;          w += (size_t)1152 * 1024 * 4;
  unsigned short* xh     = (unsigned short*)w; w += (size_t)1152 * 1024 * 2;
  unsigned short* xl     = (unsigned short*)w; w += (size_t)1152 * 1024 * 2;
  float*          proj   = (float*)w;          w += (size_t)1152 * PROJP * 4;
  float*          ybuf   = (float*)w;          w += (size_t)1152 * 2048 * 4;
  unsigned short* yh     = (unsigned short*)w; w += (size_t)1152 * 2048 * 2;
  unsigned short* yl     = (unsigned short*)w; w += (size_t)1152 * 2048 * 2;
  float*          dtt    = (float*)w;          w += (size_t)Bb * HH * Tt * 4;
  double*         dcum   = (double*)w;         w += (size_t)Bb * HH * Tt * 8;
  float*          Stb    = (float*)w;          w += (size_t)Bb * Tt * Tt * 4;
  float*          pooled = (float*)w;          w += (size_t)4096 * 4;
  unsigned short* wth    = (unsigned short*)w; w += (size_t)PROJP * 1024 * 2;
  unsigned short* wtl    = (unsigned short*)w; w += (size_t)PROJP * 1024 * 2;

  // extended region: all-layer pre-converted weights (~330 MB)
  unsigned short* wtin_h  = (unsigned short*)w; w += (size_t)NLl * PROJP * 1024 * 2;
  unsigned short* wtin_l  = (unsigned short*)w; w += (size_t)NLl * PROJP * 1024 * 2;
  unsigned short* wtout_h = (unsigned short*)w; w += (size_t)NLl * 1024 * 2048 * 2;
  unsigned short* wtout_l = (unsigned short*)w; w += (size_t)NLl * 1024 * 2048 * 2;
  unsigned short* wtv_h   = (unsigned short*)w; w += (size_t)1024 * 1024 * 2;   // z=0
  unsigned short* wtq_h   = (unsigned short*)w; w += (size_t)1024 * 1024 * 2;   // z=1
  unsigned short* wtv_l   = (unsigned short*)w; w += (size_t)1024 * 1024 * 2;
  unsigned short* wtq_l   = (unsigned short*)w; w += (size_t)1024 * 1024 * 2;
  const bool batched = ((size_t)(w - (char*)d_ws)) <= ws_size;

  dim3 blk(256);

  // ---- activations -> split bf16 (vis+qry in one launch) ----
  cvt_act_k<<<576, blk, 0, stream>>>(visual, query, xh, xl);

  if (batched) {
    // ---- all weight conversions upfront (3 launches instead of 24 in-loop) ----
    cvt_tr2_k<<<dim3(32, 16, 2), blk, 0, stream>>>(
        vis_w, wtv_h, wtv_l, 1024, 1024, 0, (size_t)1024 * 1024, qry_w);
    cvt_tr2_k<<<dim3(PROJP / 32, 16, NLl), blk, 0, stream>>>(
        in_ws, wtin_h, wtin_l, Dd, PROJ, (size_t)Dd * PROJ, (size_t)PROJP * 1024, nullptr);
    cvt_tr2_k<<<dim3(32, 32, NLl), blk, 0, stream>>>(
        out_ws, wtout_h, wtout_l, DIi, Dd, (size_t)DIi * Dd, (size_t)1024 * 2048, nullptr);
    // merged init GEMM: rows [0,1024) vis, rows [1024,1152) qry (region 2)
    gemm3_k<64, 64, true><<<dim3(16, 18), blk, 0, stream>>>(
        xh, xl, wtv_h, wtv_l, vis_b, nullptr, hidden, 1152, 1024, 1024, 256, Tt, 0,
        wtq_h, wtq_l, qry_b, 1024, 32, 256);
  } else {
    cvt_tr2_k<<<dim3(32, 16, 1), blk, 0, stream>>>(
        vis_w, wth, wtl, 1024, 1024, 0, 0, nullptr);
    cvt_tr2_k<<<dim3(32, 16, 1), blk, 0, stream>>>(
        qry_w, wth + (size_t)1024 * 1024, wtl + (size_t)1024 * 1024,
        1024, 1024, 0, 0, nullptr);
    gemm3_k<64, 64, true><<<dim3(16, 18), blk, 0, stream>>>(
        xh, xl, wth, wtl, vis_b, nullptr, hidden, 1152, 1024, 1024, 256, Tt, 0,
        wth + (size_t)1024 * 1024, wtl + (size_t)1024 * 1024, qry_b, 1024, 32, 256);
  }

  for (int i = 0; i < NLl; i++) {
    rmsnorm2_k<<<Bb * Tt, blk, 0, stream>>>(hidden, norm_ws + i * Dd, xh, xl);
    // in-proj: W [1024][4384] -> Wt [4480][1024]; C = proj [1152][4480]
    const unsigned short *bih, *bil;
    if (batched) {
      bih = wtin_h + (size_t)i * PROJP * 1024;
      bil = wtin_l + (size_t)i * PROJP * 1024;
    } else {
      cvt_tr2_k<<<dim3(PROJP / 32, 16, 1), blk, 0, stream>>>(
          in_ws + (size_t)i * Dd * PROJ, wth, wtl, Dd, PROJ, 0, 0, nullptr);
      bih = wth; bil = wtl;
    }
    gemm3_k<128, 128, false><<<dim3(PROJP / 128, 9), blk, 0, stream>>>(
        xh, xl, bih, bil, nullptr, nullptr, proj, 1152, PROJP, Dd, 1152, 0, 0,
        nullptr, nullptr, nullptr, NONE, 1, 0);
    // SSD quadratic form: merged dtcum + cbgemm, then ssd_y
    sscb_k<<<dim3(9, 10, Bb), blk, 0, stream>>>(proj, dt_biases + i * HH,
                                                A_logs + i * HH, dtt, dcum, Stb);
    ssd_y_k<<<dim3(9, HH, Bb), blk, 0, stream>>>(proj, Stb, dtt, dcum,
                                                 D_ssm + i * HH, ybuf);
    gate_norm2_k<<<Bb * Tt, blk, 0, stream>>>(ybuf, proj, gnorm_ws + i * DIi, yh, yl);
    // out-proj: W [2048][1024] -> Wt [1024][2048]; C = hidden (+res)
    const unsigned short *boh, *bol;
    if (batched) {
      boh = wtout_h + (size_t)i * 1024 * 2048;
      bol = wtout_l + (size_t)i * 1024 * 2048;
    } else {
      cvt_tr2_k<<<dim3(32, 32, 1), blk, 0, stream>>>(
          out_ws + (size_t)i * DIi * Dd, wth, wtl, DIi, Dd, 0, 0, nullptr);
      boh = wth; bol = wtl;
    }
    gemm3_k<64, 64, true><<<dim3(16, 18), blk, 0, stream>>>(
        yh, yl, boh, bol, nullptr, hidden, hidden, 1152, Dd, DIi, 1152, 0, 0,
        nullptr, nullptr, nullptr, NONE, 1, 0);
  }

  rmsnorm_k<<<Bb * Tt, blk, 0, stream>>>(hidden, norm_f_w, ybuf);
  pool_k<<<dim3(Bb, 4), blk, 0, stream>>>(ybuf, pooled);
  gemm_k<<<dim3(24, 1), blk, 0, stream>>>(pooled, head_w, head_b, nullptr, out,
                                          Bb, EE, Dd, Bb, 0, 0);
  l2norm_k<<<Bb, blk, 0, stream>>>(out);
}

// Round 6
// 2562.774 us; speedup vs baseline: 1.2149x; 1.0475x over previous
//
#include <hip/hip_runtime.h>
#include <cmath>

// Shapes (fixed by the problem)
#define Bb   4
#define Tt   288      // NV(256) + NQ(32)
#define Dd   1024
#define DIi  2048
#define HH   32
#define PP   64
#define NNs  128
#define PROJ  4384    // 2*DI + 2*N + H (logical)
#define PROJP 4480    // padded to 35*128 for MFMA tiles
#define NLl  12
#define EE   1536

typedef __bf16 bf16x8 __attribute__((ext_vector_type(8)));
typedef float f32x4 __attribute__((ext_vector_type(4)));
typedef unsigned short ushort8 __attribute__((ext_vector_type(8)));

__device__ __forceinline__ unsigned short f2bf(float v) {
  __bf16 b = (__bf16)v;
  return __builtin_bit_cast(unsigned short, b);
}
__device__ __forceinline__ float bf2f(unsigned short u) {
  unsigned int x = ((unsigned int)u) << 16;
  return __builtin_bit_cast(float, x);
}
// split fp32 -> (hi, lo) bf16 pair: v ~= hi + lo to ~16 mantissa bits
__device__ __forceinline__ void split2(float v, unsigned short& h, unsigned short& l) {
  h = f2bf(v);
  l = f2bf(v - bf2f(h));
}

// async global->LDS, 16B per lane (lane-linear LDS layout required)
__device__ __forceinline__ void async16(const void* g, void* l) {
  __builtin_amdgcn_global_load_lds(
      (const __attribute__((address_space(1))) unsigned int*)g,
      (__attribute__((address_space(3))) unsigned int*)l, 16, 0, 0);
}

// ---------------- block reduction helper ----------------
__device__ inline float block_reduce_sum(float v, float* lds) {
#pragma unroll
  for (int d = 32; d > 0; d >>= 1) v += __shfl_down(v, d, 64);
  int lane = threadIdx.x & 63;
  int w = threadIdx.x >> 6;
  if (lane == 0) lds[w] = v;
  __syncthreads();
  if (threadIdx.x == 0) {
    float s = lds[0];
    int nw = blockDim.x >> 6;
    for (int i = 1; i < nw; i++) s += lds[i];
    lds[0] = s;
  }
  __syncthreads();
  return lds[0];
}

// ---------------- fp32 -> bf16 hi/lo (activations, vis+qry fused, row-major) ----------------
__global__ __launch_bounds__(256) void cvt_act_k(const float* __restrict__ vis,
                                                 const float* __restrict__ qry,
                                                 unsigned short* __restrict__ oh,
                                                 unsigned short* __restrict__ ol) {
  int idx = (blockIdx.x * 256 + threadIdx.x) * 8;
  const float* src = (idx < 1024 * 1024) ? &vis[idx] : &qry[idx - 1024 * 1024];
  float4 v0 = *(const float4*)&src[0];
  float4 v1 = *(const float4*)&src[4];
  unsigned short h[8], l[8];
  split2(v0.x, h[0], l[0]); split2(v0.y, h[1], l[1]);
  split2(v0.z, h[2], l[2]); split2(v0.w, h[3], l[3]);
  split2(v1.x, h[4], l[4]); split2(v1.y, h[5], l[5]);
  split2(v1.z, h[6], l[6]); split2(v1.w, h[7], l[7]);
  *(ushort8*)&oh[idx] = *(const ushort8*)h;
  *(ushort8*)&ol[idx] = *(const ushort8*)l;
}

// ---------------- W fp32 [K][N] -> Wt hi/lo bf16 [Npad][K] (transpose+split+pad) ----------------
// Block covers 32 n x 64 k. Store phase: 8 consecutive tids write one row's
// 128B contiguous (16B/thread) -> coalesced. W2: optional second source for z==1.
__global__ __launch_bounds__(256) void cvt_tr2_k(const float* __restrict__ W,
                                                 unsigned short* __restrict__ Wth,
                                                 unsigned short* __restrict__ Wtl,
                                                 int K, int N,
                                                 size_t wstride, size_t ostride,
                                                 const float* __restrict__ W2) {
  __shared__ float tile[64][33];
  const float* Wp = (blockIdx.z == 1 && W2) ? W2 : W + (size_t)blockIdx.z * wstride;
  Wth += (size_t)blockIdx.z * ostride;
  Wtl += (size_t)blockIdx.z * ostride;
  const int n0 = blockIdx.x * 32, k0 = blockIdx.y * 64;
  const int c = threadIdx.x & 31;
  const int r0 = threadIdx.x >> 5;   // 0..7
#pragma unroll
  for (int j = 0; j < 8; j++) {
    int r = r0 + j * 8;              // 0..63
    int n = n0 + c;
    tile[r][c] = (n < N) ? Wp[(size_t)(k0 + r) * N + n] : 0.f;
  }
  __syncthreads();
  const int nl = threadIdx.x >> 3;   // 0..31 (row of output)
  const int kg = threadIdx.x & 7;    // 0..7  (16B chunk within row)
  unsigned short h[8], l[8];
#pragma unroll
  for (int j = 0; j < 8; j++) split2(tile[kg * 8 + j][nl], h[j], l[j]);
  size_t o = (size_t)(n0 + nl) * K + k0 + kg * 8;
  *(ushort8*)&Wth[o] = *(const ushort8*)h;
  *(ushort8*)&Wtl[o] = *(const ushort8*)l;
}

// ---------------- split-bf16 MFMA GEMM, B^T, 3-term (hi*hi + hi*lo + lo*hi) ----------------
// 16x16x32 frags (R4-proven). DBUF: double-buffered LDS, stage(next) issued
// BEFORE compute(cur), ONE barrier per k-step (guide T3-minimal 2-phase).
// Keep total LDS <= 48KB (3 blocks/CU) — 64KB is the m132/R3 occupancy cliff.
// Region-2 params (Wh2/...): rows m >= m_split use the second weight/bias and
// row-mapping — used to merge the vis+qry init GEMMs into one dispatch.
template<int BM, int BN, bool DBUF>
__global__ __launch_bounds__(256) void gemm3_k(
    const unsigned short* __restrict__ Ah, const unsigned short* __restrict__ Al,
    const unsigned short* __restrict__ Wh, const unsigned short* __restrict__ Wl,
    const float* __restrict__ bias, const float* __restrict__ res,
    float* __restrict__ C, int M, int N, int K,
    int rows_per_b, int T_total, int t_off,
    const unsigned short* __restrict__ Wh2, const unsigned short* __restrict__ Wl2,
    const float* __restrict__ bias2, int m_split, int rows_per_b2, int t_off2)
{
  constexpr int FM = BM / 32;   // frags per wave (m)
  constexpr int FN = BN / 32;   // frags per wave (n)
  constexpr int NB = DBUF ? 2 : 1;
  __shared__ __align__(16) unsigned short Ash[NB][BM * 32];
  __shared__ __align__(16) unsigned short Asl[NB][BM * 32];
  __shared__ __align__(16) unsigned short Bsh[NB][BN * 32];
  __shared__ __align__(16) unsigned short Bsl[NB][BN * 32];
  const int tid = threadIdx.x;
  const int lane = tid & 63;
  const int wm = (tid >> 6) >> 1;
  const int wn = (tid >> 6) & 1;
  const int m0 = blockIdx.y * BM;
  const int n0 = blockIdx.x * BN;
  const bool reg2 = (m0 >= m_split);
  const unsigned short* WhS = reg2 ? Wh2 : Wh;
  const unsigned short* WlS = reg2 ? Wl2 : Wl;
  const int lrow = lane & 15;
  const int lkb = (lane >> 4) * 8;   // k-element offset within tile

  f32x4 acc[FM][FN];
#pragma unroll
  for (int i = 0; i < FM; i++)
#pragma unroll
    for (int j = 0; j < FN; j++) acc[i][j] = (f32x4)0.0f;

  auto stage = [&](int bf, int k0) {
#pragma unroll
    for (int c = 0; c < BM / 64; c++) {
      int o = (c * 256 + tid) * 16;    // byte offset (row-major [BM][32] bf16 = 64B/row)
      int row = o >> 6;
      int colb = o & 63;
      size_t gb = ((size_t)(m0 + row) * K + k0) * 2 + colb;
      async16((const char*)Ah + gb, (char*)Ash[bf] + o);
      async16((const char*)Al + gb, (char*)Asl[bf] + o);
    }
#pragma unroll
    for (int c = 0; c < BN / 64; c++) {
      int o = (c * 256 + tid) * 16;
      int row = o >> 6;
      int colb = o & 63;
      size_t gb = ((size_t)(n0 + row) * K + k0) * 2 + colb;
      async16((const char*)WhS + gb, (char*)Bsh[bf] + o);
      async16((const char*)WlS + gb, (char*)Bsl[bf] + o);
    }
  };

  auto compute = [&](int bf) {
    bf16x8 ah[FM], al[FM], bh[FN], bl[FN];
#pragma unroll
    for (int i = 0; i < FM; i++) {
      int off = (wm * (FM * 16) + i * 16 + lrow) * 32 + lkb;
      ah[i] = *(const bf16x8*)&Ash[bf][off];
      al[i] = *(const bf16x8*)&Asl[bf][off];
    }
#pragma unroll
    for (int j = 0; j < FN; j++) {
      int off = (wn * (FN * 16) + j * 16 + lrow) * 32 + lkb;
      bh[j] = *(const bf16x8*)&Bsh[bf][off];
      bl[j] = *(const bf16x8*)&Bsl[bf][off];
    }
#pragma unroll
    for (int i = 0; i < FM; i++)
#pragma unroll
      for (int j = 0; j < FN; j++) {
        acc[i][j] = __builtin_amdgcn_mfma_f32_16x16x32_bf16(ah[i], bh[j], acc[i][j], 0, 0, 0);
        acc[i][j] = __builtin_amdgcn_mfma_f32_16x16x32_bf16(ah[i], bl[j], acc[i][j], 0, 0, 0);
        acc[i][j] = __builtin_amdgcn_mfma_f32_16x16x32_bf16(al[i], bh[j], acc[i][j], 0, 0, 0);
      }
  };

  if (DBUF) {
    stage(0, 0);
    __syncthreads();
    int cur = 0;
    for (int k0 = 0; k0 < K; k0 += 32) {
      if (k0 + 32 < K) stage(cur ^ 1, k0 + 32);   // async into other buffer
      compute(cur);
      __syncthreads();   // drains next-buffer loads; protects cur for overwrite
      cur ^= 1;
    }
  } else {
    for (int k0 = 0; k0 < K; k0 += 32) {
      stage(0, k0);
      __syncthreads();
      compute(0);
      __syncthreads();
    }
  }

  const float* BI = reg2 ? bias2 : bias;
  const int rpb  = reg2 ? rows_per_b2 : rows_per_b;
  const int tof  = reg2 ? t_off2 : t_off;
  const int msub = reg2 ? m_split : 0;
  const int erow = (lane >> 4) * 4;
#pragma unroll
  for (int i = 0; i < FM; i++) {
    int mbase = m0 + wm * (FM * 16) + i * 16 + erow;
#pragma unroll
    for (int j = 0; j < FN; j++) {
      int ncol = n0 + wn * (FN * 16) + j * 16 + lrow;
      float bv = BI ? BI[ncol] : 0.f;
#pragma unroll
      for (int e = 0; e < 4; e++) {
        int m = mbase + e;
        int mm = m - msub;
        size_t orow;
        if (T_total) {
          int bbv = mm / rpb;
          orow = (size_t)bbv * T_total + (mm - bbv * rpb) + tof;
        } else {
          orow = (size_t)m;
        }
        float v = acc[i][j][e] + bv;
        if (res) v += res[orow * N + ncol];
        C[orow * N + ncol] = v;
      }
    }
  }
}

// ---------------- general tiled fp32 GEMM (tiny head matmul only) ----------------
__global__ __launch_bounds__(256) void gemm_k(
    const float* __restrict__ A, const float* __restrict__ W,
    const float* __restrict__ bias, const float* __restrict__ res,
    float* __restrict__ C, int M, int N, int K,
    int rows_per_b, int T_total, int t_off)
{
  __shared__ float As[16][64];
  __shared__ float Ws[16][64];
  const int tid = threadIdx.x;
  const int tx = tid & 15;
  const int ty = tid >> 4;
  const int m0 = blockIdx.y * 64;
  const int n0 = blockIdx.x * 64;
  float acc[4][4] = {};
  const int ar = tid >> 2;
  const int ac = (tid & 3) << 2;
  const int wr = tid >> 4;
  const int wc = (tid & 15) << 2;

  for (int k0 = 0; k0 < K; k0 += 16) {
    float4 av = {0.f, 0.f, 0.f, 0.f};
    int gr = m0 + ar;
    if (gr < M) av = *(const float4*)&A[(size_t)gr * K + k0 + ac];
    As[ac + 0][ar] = av.x; As[ac + 1][ar] = av.y;
    As[ac + 2][ar] = av.z; As[ac + 3][ar] = av.w;

    float4 wv = {0.f, 0.f, 0.f, 0.f};
    int gc = n0 + wc;
    const float* wp = &W[(size_t)(k0 + wr) * N + gc];
    if (gc + 3 < N) {
      wv = *(const float4*)wp;
    } else {
      if (gc + 0 < N) wv.x = wp[0];
      if (gc + 1 < N) wv.y = wp[1];
      if (gc + 2 < N) wv.z = wp[2];
    }
    *(float4*)&Ws[wr][wc] = wv;
    __syncthreads();
#pragma unroll
    for (int kk = 0; kk < 16; kk++) {
      float4 a4 = *(const float4*)&As[kk][ty << 2];
      float4 b4 = *(const float4*)&Ws[kk][tx << 2];
      float a[4] = {a4.x, a4.y, a4.z, a4.w};
      float b[4] = {b4.x, b4.y, b4.z, b4.w};
#pragma unroll
      for (int i = 0; i < 4; i++)
#pragma unroll
        for (int j = 0; j < 4; j++)
          acc[i][j] = fmaf(a[i], b[j], acc[i][j]);
    }
    __syncthreads();
  }
#pragma unroll
  for (int i = 0; i < 4; i++) {
    int gr = m0 + (ty << 2) + i;
    if (gr >= M) continue;
    int bbv = gr / rows_per_b;
    int tt = gr - bbv * rows_per_b;
    size_t orow = (size_t)bbv * T_total + tt + t_off;
#pragma unroll
    for (int j = 0; j < 4; j++) {
      int gc = n0 + (tx << 2) + j;
      if (gc >= N) continue;
      float v = acc[i][j];
      if (bias) v += bias[gc];
      if (res)  v += res[orow * (size_t)N + gc];
      C[orow * (size_t)N + gc] = v;
    }
  }
}

// ---------------- RMSNorm (fp32 out, for final norm) ----------------
__global__ __launch_bounds__(256) void rmsnorm_k(
    const float* __restrict__ x, const float* __restrict__ w, float* __restrict__ out)
{
  __shared__ float lds[8];
  const int row = blockIdx.x;
  const float* xr = x + (size_t)row * Dd;
  float4 v = *(const float4*)&xr[threadIdx.x << 2];
  float ss = v.x * v.x + v.y * v.y + v.z * v.z + v.w * v.w;
  ss = block_reduce_sum(ss, lds);
  float sc = rsqrtf(ss * (1.f / Dd) + 1e-5f);
  float4 wv = *(const float4*)&w[threadIdx.x << 2];
  float4 o = {v.x * sc * wv.x, v.y * sc * wv.y, v.z * sc * wv.z, v.w * sc * wv.w};
  *(float4*)&out[(size_t)row * Dd + (threadIdx.x << 2)] = o;
}

// ---------------- RMSNorm (bf16 hi/lo out, feeds split GEMM) ----------------
__global__ __launch_bounds__(256) void rmsnorm2_k(
    const float* __restrict__ x, const float* __restrict__ w,
    unsigned short* __restrict__ oh, unsigned short* __restrict__ ol)
{
  __shared__ float lds[8];
  const int row = blockIdx.x;
  const float* xr = x + (size_t)row * Dd;
  float4 v = *(const float4*)&xr[threadIdx.x << 2];
  float ss = v.x * v.x + v.y * v.y + v.z * v.z + v.w * v.w;
  ss = block_reduce_sum(ss, lds);
  float sc = rsqrtf(ss * (1.f / Dd) + 1e-5f);
  float4 wv = *(const float4*)&w[threadIdx.x << 2];
  ushort4 h, l;
  split2(v.x * sc * wv.x, h.x, l.x);
  split2(v.y * sc * wv.y, h.y, l.y);
  split2(v.z * sc * wv.z, h.z, l.z);
  split2(v.w * sc * wv.w, h.w, l.w);
  size_t o = (size_t)row * Dd + (threadIdx.x << 2);
  *(ushort4*)&oh[o] = h;
  *(ushort4*)&ol[o] = l;
}

// ---------------- merged: dtcum (y==9) + cbgemm (y<9) ----------------
// Both only READ proj; writes are disjoint -> safe to fuse into one dispatch.
__global__ __launch_bounds__(256) void sscb_k(const float* __restrict__ proj,
                                              const float* __restrict__ dt_bias,
                                              const float* __restrict__ A_log,
                                              float* __restrict__ dtt,
                                              double* __restrict__ dcum,
                                              float* __restrict__ St)
{
  __shared__ float Ct[32][130];
  __shared__ float Bt[32][130];
  if (blockIdx.y == 9) {
    // dt = softplus(.), cum = prefix-sum(dt*A) in fp64; wave per (b,h)
    if (blockIdx.x >= 8) return;
    const int wv = threadIdx.x >> 6;
    const int lane = threadIdx.x & 63;
    const int h = blockIdx.x * 4 + wv;
    const int b = blockIdx.z;
    const float A = -expf(A_log[h]);
    const float bias = dt_bias[h];
    const int rowo = (b * HH + h) * Tt;
    double base = 0.0;
    for (int c = 0; c < (Tt + 63) / 64; c++) {
      int t = c * 64 + lane;
      float dt = 0.f;
      if (t < Tt) {
        float v = proj[(size_t)(b * Tt + t) * PROJP + 2 * DIi + 2 * NNs + h] + bias;
        dt = (v > 20.f) ? v : log1pf(expf(v));
      }
      double a = (double)(dt * A);
#pragma unroll
      for (int d = 1; d < 64; d <<= 1) {
        double o = __shfl_up(a, d, 64);
        if (lane >= d) a += o;
      }
      double cum = base + a;
      if (t < Tt) { dtt[rowo + t] = dt; dcum[rowo + t] = cum; }
      base = __shfl(cum, 63, 64);
    }
    return;
  }
  // St[b][j][t] = B[b,j,:]·C[b,t,:] (32x32 tiles, causal only)
  const int tI = blockIdx.x, jI = blockIdx.y, b = blockIdx.z;
  if (jI > tI) return;
  const int tid = threadIdx.x;
  const int r = tid >> 3;          // 0..31
  const int q = (tid & 7) * 16;    // 16 floats each
  const float* pb = proj + (size_t)b * Tt * PROJP;
  {
    const float* crow = pb + (size_t)(tI * 32 + r) * PROJP + 2 * DIi + NNs + q;
    const float* brow = pb + (size_t)(jI * 32 + r) * PROJP + 2 * DIi + q;
#pragma unroll
    for (int f = 0; f < 16; f += 4) {
      float4 c4 = *(const float4*)&crow[f];
      float4 b4 = *(const float4*)&brow[f];
      *(float2*)&Ct[r][q + f]     = make_float2(c4.x, c4.y);
      *(float2*)&Ct[r][q + f + 2] = make_float2(c4.z, c4.w);
      *(float2*)&Bt[r][q + f]     = make_float2(b4.x, b4.y);
      *(float2*)&Bt[r][q + f + 2] = make_float2(b4.z, b4.w);
    }
  }
  __syncthreads();
  const int j_r = tid >> 3;
  const int t_c = (tid & 7) * 4;
  float acc[4] = {0.f, 0.f, 0.f, 0.f};
  for (int n = 0; n < NNs; n += 2) {
    float2 b2 = *(const float2*)&Bt[j_r][n];
#pragma unroll
    for (int k = 0; k < 4; k++) {
      float2 c2 = *(const float2*)&Ct[t_c + k][n];
      acc[k] = fmaf(b2.x, c2.x, acc[k]);
      acc[k] = fmaf(b2.y, c2.y, acc[k]);
    }
  }
  float* so = St + ((size_t)b * Tt + jI * 32 + j_r) * Tt + tI * 32 + t_c;
  *(float4*)so = make_float4(acc[0], acc[1], acc[2], acc[3]);
}

// ---------------- Y[b,t,h,:] = sum_j M(t,j) * X[b,j,h,:]  (causal, decay-scaled) ----------------
__global__ __launch_bounds__(256) void ssd_y_k(
    const float* __restrict__ proj, const float* __restrict__ St,
    const float* __restrict__ dtt, const double* __restrict__ dcum,
    const float* __restrict__ Dssm, float* __restrict__ ybuf)
{
  const int tI = blockIdx.x;          // 0..8
  const int h  = blockIdx.y;
  const int b  = blockIdx.z;
  __shared__ __align__(16) float Xs[32][64];
  __shared__ __align__(16) float Ss[32][36];   // Ss[j][t], stride 36: conflict-free on t
  __shared__ double cjs[32];
  const int tid = threadIdx.x;
  const int t_l = tid & 31;
  const int pg  = tid >> 5;           // 0..7
  const int t0  = tI * 32;
  const int rowo = (b * HH + h) * Tt;
  const double ct = dcum[rowo + t0 + t_l];
  const float Ds = Dssm[h];
  const float* pb = proj + (size_t)b * Tt * PROJP;
  float y[8] = {0,0,0,0,0,0,0,0};
  const int sr = tid >> 3;            // staging row 0..31
  const int sq = tid & 7;

  for (int jI = 0; jI <= tI; jI++) {
    const int j0 = jI * 32;
    {   // X tile [32 j][64 p] from xss slice
      const float* xr = pb + (size_t)(j0 + sr) * PROJP + DIi + h * PP + sq * 8;
      *(float4*)&Xs[sr][sq * 8]     = *(const float4*)&xr[0];
      *(float4*)&Xs[sr][sq * 8 + 4] = *(const float4*)&xr[4];
    }
    {   // S^T tile scaled by dt_j
      const float* srow = St + ((size_t)b * Tt + j0 + sr) * Tt + t0 + sq * 4;
      float4 s4 = *(const float4*)srow;
      float dj = dtt[rowo + j0 + sr];
      s4.x *= dj; s4.y *= dj; s4.z *= dj; s4.w *= dj;
      *(float4*)&Ss[sr][sq * 4] = s4;
    }
    if (tid < 32) cjs[tid] = dcum[rowo + j0 + tid];
    __syncthreads();

    if (jI < tI) {
#pragma unroll 4
      for (int j = 0; j < 32; j++) {
        float d = (float)(ct - cjs[j]);
        float m = Ss[j][t_l] * expf(fminf(d, 0.f));
        const float* xp = &Xs[j][pg * 8];
        float4 a0 = *(const float4*)&xp[0];
        float4 a1 = *(const float4*)&xp[4];
        y[0] = fmaf(m, a0.x, y[0]); y[1] = fmaf(m, a0.y, y[1]);
        y[2] = fmaf(m, a0.z, y[2]); y[3] = fmaf(m, a0.w, y[3]);
        y[4] = fmaf(m, a1.x, y[4]); y[5] = fmaf(m, a1.y, y[5]);
        y[6] = fmaf(m, a1.z, y[6]); y[7] = fmaf(m, a1.w, y[7]);
      }
    } else {   // diagonal tile: causal mask + diagonal formula
      for (int j = 0; j < 32; j++) {
        float sv = Ss[j][t_l];
        float d = (float)(ct - cjs[j]);
        float m = sv * expf(fminf(d, 0.f));
        if (j == t_l) m = 0.5f * sv + Ds;
        if (j > t_l)  m = 0.f;
        const float* xp = &Xs[j][pg * 8];
        float4 a0 = *(const float4*)&xp[0];
        float4 a1 = *(const float4*)&xp[4];
        y[0] = fmaf(m, a0.x, y[0]); y[1] = fmaf(m, a0.y, y[1]);
        y[2] = fmaf(m, a0.z, y[2]); y[3] = fmaf(m, a0.w, y[3]);
        y[4] = fmaf(m, a1.x, y[4]); y[5] = fmaf(m, a1.y, y[5]);
        y[6] = fmaf(m, a1.z, y[6]); y[7] = fmaf(m, a1.w, y[7]);
      }
    }
    __syncthreads();
  }
  float* yo = &ybuf[(size_t)(b * Tt + t0 + t_l) * DIi + h * PP + pg * 8];
  *(float4*)&yo[0] = make_float4(y[0], y[1], y[2], y[3]);
  *(float4*)&yo[4] = make_float4(y[4], y[5], y[6], y[7]);
}

// ---------------- fused silu-gate + RMSNorm over DI=2048, bf16 hi/lo out ----------------
__global__ __launch_bounds__(256) void gate_norm2_k(
    const float* __restrict__ ybuf, const float* __restrict__ proj,
    const float* __restrict__ gw,
    unsigned short* __restrict__ yh, unsigned short* __restrict__ yl)
{
  __shared__ float lds[8];
  const int row = blockIdx.x;
  const float* yr = ybuf + (size_t)row * DIi;
  const float* zr = proj + (size_t)row * PROJP;   // z = cols [0, 2048)
  const int base = threadIdx.x << 3;
  float4 z0 = *(const float4*)&zr[base];
  float4 z1 = *(const float4*)&zr[base + 4];
  float4 y0 = *(const float4*)&yr[base];
  float4 y1 = *(const float4*)&yr[base + 4];
  float zz[8] = {z0.x, z0.y, z0.z, z0.w, z1.x, z1.y, z1.z, z1.w};
  float yy[8] = {y0.x, y0.y, y0.z, y0.w, y1.x, y1.y, y1.z, y1.w};
  float g[8];
  float ss = 0.f;
#pragma unroll
  for (int e = 0; e < 8; e++) {
    float s = zz[e] / (1.f + expf(-zz[e]));
    float gv = yy[e] * s;
    g[e] = gv;
    ss += gv * gv;
  }
  ss = block_reduce_sum(ss, lds);
  float sc = rsqrtf(ss * (1.f / DIi) + 1e-5f);
  unsigned short h[8], l[8];
#pragma unroll
  for (int e = 0; e < 8; e++) split2(g[e] * sc * gw[base + e], h[e], l[e]);
  size_t o = (size_t)row * DIi + base;
  *(ushort8*)&yh[o] = *(const ushort8*)h;
  *(ushort8*)&yl[o] = *(const ushort8*)l;
}

// ---------------- mean over T ----------------
__global__ void pool_k(const float* __restrict__ xin, float* __restrict__ pooled) {
  int b = blockIdx.x;
  int d = blockIdx.y * 256 + threadIdx.x;
  const float* base = xin + (size_t)b * Tt * Dd + d;
  float s = 0.f;
  for (int t = 0; t < Tt; t++) s += base[(size_t)t * Dd];
  pooled[b * Dd + d] = s * (1.f / Tt);
}

// ---------------- L2-normalize rows of (4, 1536), in place ----------------
__global__ __launch_bounds__(256) void l2norm_k(float* __restrict__ out) {
  __shared__ float lds[8];
  const int row = blockIdx.x;
  float* r = out + (size_t)row * EE;
  float v[6];
  float ss = 0.f;
#pragma unroll
  for (int e = 0; e < 6; e++) {
    v[e] = r[(e << 8) + threadIdx.x];
    ss += v[e] * v[e];
  }
  ss = block_reduce_sum(ss, lds);
  float sc = 1.f / fmaxf(sqrtf(ss), 1e-12f);
#pragma unroll
  for (int e = 0; e < 6; e++) r[(e << 8) + threadIdx.x] = v[e] * sc;
}

// ---------------- launch ----------------
extern "C" void kernel_launch(void* const* d_in, const int* in_sizes, int n_in,
                              void* d_out, int out_size, void* d_ws, size_t ws_size,
                              hipStream_t stream) {
  (void)in_sizes; (void)n_in; (void)out_size;
  const float* visual   = (const float*)d_in[0];
  const float* query    = (const float*)d_in[1];
  const float* vis_w    = (const float*)d_in[2];
  const float* vis_b    = (const float*)d_in[3];
  const float* qry_w    = (const float*)d_in[4];
  const float* qry_b    = (const float*)d_in[5];
  const float* norm_ws  = (const float*)d_in[6];
  const float* in_ws    = (const float*)d_in[7];
  const float* dt_biases= (const float*)d_in[8];
  const float* A_logs   = (const float*)d_in[9];
  const float* D_ssm    = (const float*)d_in[10];
  const float* gnorm_ws = (const float*)d_in[11];
  const float* out_ws   = (const float*)d_in[12];
  const float* norm_f_w = (const float*)d_in[13];
  const float* head_w   = (const float*)d_in[14];
  const float* head_b   = (const float*)d_in[15];
  float* out = (float*)d_out;
  const int NONE = 0x7fffffff;

  // workspace layout (bytes), all 16B-aligned; base ~69 MB
  char* w = (char*)d_ws;
  float*          hidden = (float*)w;          w += (size_t)1152 * 1024 * 4;
  unsigned short* xh     = (unsigned short*)w; w += (size_t)1152 * 1024 * 2;
  unsigned short* xl     = (unsigned short*)w; w += (size_t)1152 * 1024 * 2;
  float*          proj   = (float*)w;          w += (size_t)1152 * PROJP * 4;
  float*          ybuf   = (float*)w;          w += (size_t)1152 * 2048 * 4;
  unsigned short* yh     = (unsigned short*)w; w += (size_t)1152 * 2048 * 2;
  unsigned short* yl     = (unsigned short*)w; w += (size_t)1152 * 2048 * 2;
  float*          dtt    = (float*)w;          w += (size_t)Bb * HH * Tt * 4;
  double*         dcum   = (double*)w;         w += (size_t)Bb * HH * Tt * 8;
  float*          Stb    = (float*)w;          w += (size_t)Bb * Tt * Tt * 4;
  float*          pooled = (float*)w;          w += (size_t)4096 * 4;
  unsigned short* wth    = (unsigned short*)w; w += (size_t)PROJP * 1024 * 2;
  unsigned short* wtl    = (unsigned short*)w; w += (size_t)PROJP * 1024 * 2;

  // extended region: all-layer pre-converted weights (~330 MB)
  unsigned short* wtin_h  = (unsigned short*)w; w += (size_t)NLl * PROJP * 1024 * 2;
  unsigned short* wtin_l  = (unsigned short*)w; w += (size_t)NLl * PROJP * 1024 * 2;
  unsigned short* wtout_h = (unsigned short*)w; w += (size_t)NLl * 1024 * 2048 * 2;
  unsigned short* wtout_l = (unsigned short*)w; w += (size_t)NLl * 1024 * 2048 * 2;
  unsigned short* wtv_h   = (unsigned short*)w; w += (size_t)1024 * 1024 * 2;   // z=0
  unsigned short* wtq_h   = (unsigned short*)w; w += (size_t)1024 * 1024 * 2;   // z=1
  unsigned short* wtv_l   = (unsigned short*)w; w += (size_t)1024 * 1024 * 2;
  unsigned short* wtq_l   = (unsigned short*)w; w += (size_t)1024 * 1024 * 2;
  const bool batched = ((size_t)(w - (char*)d_ws)) <= ws_size;

  dim3 blk(256);

  // ---- activations -> split bf16 (vis+qry in one launch) ----
  cvt_act_k<<<576, blk, 0, stream>>>(visual, query, xh, xl);

  if (batched) {
    // ---- all weight conversions upfront (3 launches instead of 24 in-loop) ----
    cvt_tr2_k<<<dim3(32, 16, 2), blk, 0, stream>>>(
        vis_w, wtv_h, wtv_l, 1024, 1024, 0, (size_t)1024 * 1024, qry_w);
    cvt_tr2_k<<<dim3(PROJP / 32, 16, NLl), blk, 0, stream>>>(
        in_ws, wtin_h, wtin_l, Dd, PROJ, (size_t)Dd * PROJ, (size_t)PROJP * 1024, nullptr);
    cvt_tr2_k<<<dim3(32, 32, NLl), blk, 0, stream>>>(
        out_ws, wtout_h, wtout_l, DIi, Dd, (size_t)DIi * Dd, (size_t)1024 * 2048, nullptr);
    // merged init GEMM: rows [0,1024) vis, rows [1024,1152) qry (region 2)
    gemm3_k<64, 64, true><<<dim3(16, 18), blk, 0, stream>>>(
        xh, xl, wtv_h, wtv_l, vis_b, nullptr, hidden, 1152, 1024, 1024, 256, Tt, 0,
        wtq_h, wtq_l, qry_b, 1024, 32, 256);
  } else {
    cvt_tr2_k<<<dim3(32, 16, 1), blk, 0, stream>>>(
        vis_w, wth, wtl, 1024, 1024, 0, 0, nullptr);
    cvt_tr2_k<<<dim3(32, 16, 1), blk, 0, stream>>>(
        qry_w, wth + (size_t)1024 * 1024, wtl + (size_t)1024 * 1024,
        1024, 1024, 0, 0, nullptr);
    gemm3_k<64, 64, true><<<dim3(16, 18), blk, 0, stream>>>(
        xh, xl, wth, wtl, vis_b, nullptr, hidden, 1152, 1024, 1024, 256, Tt, 0,
        wth + (size_t)1024 * 1024, wtl + (size_t)1024 * 1024, qry_b, 1024, 32, 256);
  }

  for (int i = 0; i < NLl; i++) {
    rmsnorm2_k<<<Bb * Tt, blk, 0, stream>>>(hidden, norm_ws + i * Dd, xh, xl);
    // in-proj: W [1024][4384] -> Wt [4480][1024]; C = proj [1152][4480]
    const unsigned short *bih, *bil;
    if (batched) {
      bih = wtin_h + (size_t)i * PROJP * 1024;
      bil = wtin_l + (size_t)i * PROJP * 1024;
    } else {
      cvt_tr2_k<<<dim3(PROJP / 32, 16, 1), blk, 0, stream>>>(
          in_ws + (size_t)i * Dd * PROJ, wth, wtl, Dd, PROJ, 0, 0, nullptr);
      bih = wth; bil = wtl;
    }
    // <128,64> DBUF: 48KB LDS -> 3 blocks/CU (avoids 64KB cliff); grid 630
    // blocks halves the 315-block wave-quantization tail.
    gemm3_k<128, 64, true><<<dim3(PROJP / 64, 9), blk, 0, stream>>>(
        xh, xl, bih, bil, nullptr, nullptr, proj, 1152, PROJP, Dd, 1152, 0, 0,
        nullptr, nullptr, nullptr, NONE, 1, 0);
    // SSD quadratic form: merged dtcum + cbgemm, then ssd_y
    sscb_k<<<dim3(9, 10, Bb), blk, 0, stream>>>(proj, dt_biases + i * HH,
                                                A_logs + i * HH, dtt, dcum, Stb);
    ssd_y_k<<<dim3(9, HH, Bb), blk, 0, stream>>>(proj, Stb, dtt, dcum,
                                                 D_ssm + i * HH, ybuf);
    gate_norm2_k<<<Bb * Tt, blk, 0, stream>>>(ybuf, proj, gnorm_ws + i * DIi, yh, yl);
    // out-proj: W [2048][1024] -> Wt [1024][2048]; C = hidden (+res)
    const unsigned short *boh, *bol;
    if (batched) {
      boh = wtout_h + (size_t)i * 1024 * 2048;
      bol = wtout_l + (size_t)i * 1024 * 2048;
    } else {
      cvt_tr2_k<<<dim3(32, 32, 1), blk, 0, stream>>>(
          out_ws + (size_t)i * DIi * Dd, wth, wtl, DIi, Dd, 0, 0, nullptr);
      boh = wth; bol = wtl;
    }
    gemm3_k<64, 64, true><<<dim3(16, 18), blk, 0, stream>>>(
        yh, yl, boh, bol, nullptr, hidden, hidden, 1152, Dd, DIi, 1152, 0, 0,
        nullptr, nullptr, nullptr, NONE, 1, 0);
  }

  rmsnorm_k<<<Bb * Tt, blk, 0, stream>>>(hidden, norm_f_w, ybuf);
  pool_k<<<dim3(Bb, 4), blk, 0, stream>>>(ybuf, pooled);
  gemm_k<<<dim3(24, 1), blk, 0, stream>>>(pooled, head_w, head_b, nullptr, out,
                                          Bb, EE, Dd, Bb, 0, 0);
  l2norm_k<<<Bb, blk, 0, stream>>>(out);
}